// Round 1
// baseline (634.615 us; speedup 1.0000x reference)
//
#include <hip/hip_runtime.h>
#include <math.h>

#define Hh 22
#define Ww 22
#define P_ 484   // H*W
#define Fn 484   // number of filters (H*W)
#define S_ 16
#define C_ 256
#define BM 64
#define BN 64
#define BK 16

// ---------------- maps: label_map, a (target_mask), sw^2, sw ----------------
__global__ void k_maps(const float* __restrict__ label_w, const float* __restrict__ mask_w,
                       const float* __restrict__ spatial_w,
                       float* __restrict__ lmap, float* __restrict__ amap,
                       float* __restrict__ sw2map, float* __restrict__ spwmap) {
    int idx = blockIdx.x * blockDim.x + threadIdx.x;
    if (idx >= Fn * P_) return;
    int f = idx / P_, p = idx % P_;
    int i = f / Ww, j = f % Ww;
    int k = p / Ww, l = p % Ww;
    float dx = (float)(k - i), dy = (float)(l - j);
    float d = sqrtf(dx * dx + dy * dy) * 2.0f;   // dist / BIN_DISP
    float lab = 0.f, msk = 0.f, spw = 0.f;
#pragma unroll
    for (int b = 0; b < 9; ++b) {
        float wb = fmaxf(0.f, 1.f - fabsf(d - (float)b));
        lab += wb * label_w[b];
        msk += wb * mask_w[b];
        spw += wb * spatial_w[b];
    }
    float w9 = fminf(fmaxf(1.f + (d - 9.f), 0.f), 1.f);
    lab += w9 * label_w[9];
    msk += w9 * mask_w[9];
    spw += w9 * spatial_w[9];
    lmap[idx] = lab;
    amap[idx] = 1.f / (1.f + expf(-msk));
    sw2map[idx] = spw * spw;
    spwmap[idx] = spw;
}

__global__ void k_copy(const float* __restrict__ src, float* __restrict__ dst, int n) {
    int i = blockIdx.x * blockDim.x + threadIdx.x;
    if (i < n) dst[i] = src[i];
}

// ---------------- GEMM1: scores = w . f2, fused residual/mask epilogue ------
// A = Wf[s]  [Fn][C_]   (lda = C_)
// B = F2[s]  [C_][P_]   (ldb = P_)
__global__ __launch_bounds__(256) void k_gemm_scores(
    const float* __restrict__ Wf, const float* __restrict__ F2,
    const float* __restrict__ amap, const float* __restrict__ sw2map,
    const float* __restrict__ lmap,
    float* __restrict__ resid, float* __restrict__ masko) {
    int s = blockIdx.z;
    int m0 = blockIdx.y * BM;
    int n0 = blockIdx.x * BN;
    const float* A = Wf + (size_t)s * Fn * C_;
    const float* B = F2 + (size_t)s * C_ * P_;
    __shared__ float As[BK][BM + 1];
    __shared__ float Bs[BK][BN];
    int tid = threadIdx.x;
    int tx = tid & 15, ty = tid >> 4;
    float acc[4][4] = {};
    for (int k0 = 0; k0 < C_; k0 += BK) {
        {   // A tile: As[kk][m] = A[m0+m][k0+kk]
            int m = tid >> 2;
            int kk = (tid & 3) * 4;
            int gm = m0 + m;
            const float* ap = A + (size_t)gm * C_ + k0 + kk;
#pragma unroll
            for (int q = 0; q < 4; ++q)
                As[kk + q][m] = (gm < Fn) ? ap[q] : 0.f;   // C_ % BK == 0
        }
        {   // B tile: Bs[kk][n] = B[k0+kk][n0+n]
            int kk = tid >> 4;
            int n = (tid & 15) * 4;
            int gn = n0 + n;
            const float* bp = B + (size_t)(k0 + kk) * P_ + gn;
#pragma unroll
            for (int q = 0; q < 4; ++q)
                Bs[kk][n + q] = (gn + q < P_) ? bp[q] : 0.f;
        }
        __syncthreads();
#pragma unroll
        for (int kk = 0; kk < BK; ++kk) {
            float av[4], bv[4];
#pragma unroll
            for (int r = 0; r < 4; ++r) av[r] = As[kk][ty * 4 + r];
#pragma unroll
            for (int c = 0; c < 4; ++c) bv[c] = Bs[kk][tx * 4 + c];
#pragma unroll
            for (int r = 0; r < 4; ++r)
#pragma unroll
                for (int c = 0; c < 4; ++c)
                    acc[r][c] = fmaf(av[r], bv[c], acc[r][c]);
        }
        __syncthreads();
    }
#pragma unroll
    for (int r = 0; r < 4; ++r) {
        int m = m0 + ty * 4 + r;
        if (m >= Fn) continue;
#pragma unroll
        for (int c = 0; c < 4; ++c) {
            int n = n0 + tx * 4 + c;
            if (n >= P_) continue;
            float sc = acc[r][c];
            size_t mp = (size_t)m * P_ + n;
            float a = amap[mp];
            float sgn = (sc > 0.f) ? 1.f : ((sc < 0.f) ? -1.f : 0.f);
            float msk = 0.5f * (1.f - a) * sgn + 0.5f * (1.f + a);
            float res = msk * (sw2map[mp] * (msk * sc - lmap[mp]));
            size_t o = (size_t)s * Fn * P_ + mp;
            resid[o] = res;
            masko[o] = msk;
        }
    }
}

// ---------------- GEMM2: w_grad = residuals . f2^T + reg*w ------------------
// A = resid[s] [Fn][P_] (lda = P_);  B[k=p][n=c] = F2[s][c][p]
__global__ __launch_bounds__(256) void k_gemm_wgrad(
    const float* __restrict__ resid, const float* __restrict__ F2,
    const float* __restrict__ Wf, const float* __restrict__ fr_ptr,
    float* __restrict__ wgrad) {
    int s = blockIdx.z;
    int m0 = blockIdx.y * BM;   // f
    int n0 = blockIdx.x * BN;   // c
    const float* A = resid + (size_t)s * Fn * P_;
    const float* B = F2 + (size_t)s * C_ * P_;
    __shared__ float As[BK][BM + 1];
    __shared__ float Bs[BK][BN + 1];
    int tid = threadIdx.x;
    int tx = tid & 15, ty = tid >> 4;
    float acc[4][4] = {};
    for (int k0 = 0; k0 < P_; k0 += BK) {
        {   // A tile: As[kk][m] = A[m0+m][k0+kk]   (K tail: P_ % BK = 4)
            int m = tid >> 2;
            int kk = (tid & 3) * 4;
            int gm = m0 + m;
            const float* ap = A + (size_t)gm * P_ + k0 + kk;
#pragma unroll
            for (int q = 0; q < 4; ++q)
                As[kk + q][m] = (gm < Fn && (k0 + kk + q) < P_) ? ap[q] : 0.f;
        }
        {   // B tile: Bs[kk][n] = F2[s][(n0+n)][k0+kk]  (contiguous in kk)
            int n = tid >> 2;
            int kk = (tid & 3) * 4;
            const float* bp = B + (size_t)(n0 + n) * P_ + k0 + kk;
#pragma unroll
            for (int q = 0; q < 4; ++q)
                Bs[kk + q][n] = ((k0 + kk + q) < P_) ? bp[q] : 0.f;   // n0+n < C_ always
        }
        __syncthreads();
#pragma unroll
        for (int kk = 0; kk < BK; ++kk) {
            float av[4], bv[4];
#pragma unroll
            for (int r = 0; r < 4; ++r) av[r] = As[kk][ty * 4 + r];
#pragma unroll
            for (int c = 0; c < 4; ++c) bv[c] = Bs[kk][tx * 4 + c];
#pragma unroll
            for (int r = 0; r < 4; ++r)
#pragma unroll
                for (int c = 0; c < 4; ++c)
                    acc[r][c] = fmaf(av[r], bv[c], acc[r][c]);
        }
        __syncthreads();
    }
    float fr = fr_ptr[0];
    float regw = fmaxf(fr * fr, 1e-10f);
#pragma unroll
    for (int r = 0; r < 4; ++r) {
        int m = m0 + ty * 4 + r;
        if (m >= Fn) continue;
#pragma unroll
        for (int c = 0; c < 4; ++c) {
            int n = n0 + tx * 4 + c;   // < C_ always (grid exact)
            size_t o = (size_t)s * Fn * C_ + (size_t)m * C_ + n;
            wgrad[o] = acc[r][c] + regw * Wf[o];
        }
    }
}

// ---------------- GEMM3: scores_grad = w_grad . f2, fused sg^2 epilogue -----
__global__ __launch_bounds__(256) void k_gemm_sgrad(
    const float* __restrict__ wgrad, const float* __restrict__ F2,
    const float* __restrict__ maski, const float* __restrict__ spwmap,
    float* __restrict__ sg2) {
    int s = blockIdx.z;
    int m0 = blockIdx.y * BM;
    int n0 = blockIdx.x * BN;
    const float* A = wgrad + (size_t)s * Fn * C_;
    const float* B = F2 + (size_t)s * C_ * P_;
    __shared__ float As[BK][BM + 1];
    __shared__ float Bs[BK][BN];
    int tid = threadIdx.x;
    int tx = tid & 15, ty = tid >> 4;
    float acc[4][4] = {};
    for (int k0 = 0; k0 < C_; k0 += BK) {
        {
            int m = tid >> 2;
            int kk = (tid & 3) * 4;
            int gm = m0 + m;
            const float* ap = A + (size_t)gm * C_ + k0 + kk;
#pragma unroll
            for (int q = 0; q < 4; ++q)
                As[kk + q][m] = (gm < Fn) ? ap[q] : 0.f;
        }
        {
            int kk = tid >> 4;
            int n = (tid & 15) * 4;
            int gn = n0 + n;
            const float* bp = B + (size_t)(k0 + kk) * P_ + gn;
#pragma unroll
            for (int q = 0; q < 4; ++q)
                Bs[kk][n + q] = (gn + q < P_) ? bp[q] : 0.f;
        }
        __syncthreads();
#pragma unroll
        for (int kk = 0; kk < BK; ++kk) {
            float av[4], bv[4];
#pragma unroll
            for (int r = 0; r < 4; ++r) av[r] = As[kk][ty * 4 + r];
#pragma unroll
            for (int c = 0; c < 4; ++c) bv[c] = Bs[kk][tx * 4 + c];
#pragma unroll
            for (int r = 0; r < 4; ++r)
#pragma unroll
                for (int c = 0; c < 4; ++c)
                    acc[r][c] = fmaf(av[r], bv[c], acc[r][c]);
        }
        __syncthreads();
    }
#pragma unroll
    for (int r = 0; r < 4; ++r) {
        int m = m0 + ty * 4 + r;
        if (m >= Fn) continue;
#pragma unroll
        for (int c = 0; c < 4; ++c) {
            int n = n0 + tx * 4 + c;
            if (n >= P_) continue;
            size_t mp = (size_t)m * P_ + n;
            size_t o = (size_t)s * Fn * P_ + mp;
            float sg = spwmap[mp] * maski[o] * acc[r][c];
            sg2[o] = sg * sg;
        }
    }
}

// ---------------- reductions + update ---------------------------------------
__device__ __forceinline__ float block_reduce_sum(float v) {
    __shared__ float part[4];
#pragma unroll
    for (int o = 32; o > 0; o >>= 1) v += __shfl_down(v, o, 64);
    int t = threadIdx.x;
    int lane = t & 63, wv = t >> 6;
    if (lane == 0) part[wv] = v;
    __syncthreads();
    return part[0] + part[1] + part[2] + part[3];
}

__global__ __launch_bounds__(256) void k_alpha_num(const float* __restrict__ wgrad,
                                                   float* __restrict__ num) {
    int row = blockIdx.x;                 // s*Fn + f
    const float* g = wgrad + (size_t)row * C_;
    float v = g[threadIdx.x];
    float sum = block_reduce_sum(v * v);
    if (threadIdx.x == 0) num[row] = sum;
}

__global__ __launch_bounds__(256) void k_alpha(const float* __restrict__ sg2,
                                               const float* __restrict__ num,
                                               const float* __restrict__ fr_ptr,
                                               float* __restrict__ alpha) {
    int row = blockIdx.x;
    const float* g = sg2 + (size_t)row * P_;
    float v = 0.f;
    for (int i = threadIdx.x; i < P_; i += 256) v += g[i];
    float sum = block_reduce_sum(v);
    if (threadIdx.x == 0) {
        float fr = fr_ptr[0];
        float regw = fmaxf(fr * fr, 1e-10f);
        float nu = num[row];
        float den = fmaxf(sum + regw * nu, 1e-8f);
        alpha[row] = nu / den;
    }
}

__global__ __launch_bounds__(256) void k_update(float* __restrict__ Wf,
                                                const float* __restrict__ wgrad,
                                                const float* __restrict__ alpha,
                                                const float* __restrict__ lsl) {
    int i = blockIdx.x * blockDim.x + threadIdx.x;
    if (i >= S_ * Fn * C_) return;
    int row = i >> 8;   // / C_
    float step = expf(lsl[0]);
    Wf[i] -= step * alpha[row] * wgrad[i];
}

// ---------------- launch -----------------------------------------------------
extern "C" void kernel_launch(void* const* d_in, const int* in_sizes, int n_in,
                              void* d_out, int out_size, void* d_ws, size_t ws_size,
                              hipStream_t stream) {
    const float* filt = (const float*)d_in[0];   // [S][Fn][C][1][1]
    const float* feat = (const float*)d_in[1];   // [1][S][C][H][W]
    const float* lsl  = (const float*)d_in[2];
    const float* freg = (const float*)d_in[3];
    const float* lw   = (const float*)d_in[4];
    const float* mw   = (const float*)d_in[5];
    const float* sw   = (const float*)d_in[6];
    float* Wf = (float*)d_out;                   // working filter, also output

    // workspace layout (floats)
    float* ws = (float*)d_ws;
    size_t off = 0;
    float* resid  = ws + off; off += (size_t)S_ * Fn * P_;   // 3,748,096
    float* maskb  = ws + off; off += (size_t)S_ * Fn * P_;
    float* sg2    = ws + off; off += (size_t)S_ * Fn * P_;
    float* wgrad  = ws + off; off += (size_t)S_ * Fn * C_;   // 1,982,464
    float* lmap   = ws + off; off += (size_t)Fn * P_;
    float* amap   = ws + off; off += (size_t)Fn * P_;
    float* sw2map = ws + off; off += (size_t)Fn * P_;
    float* spwmap = ws + off; off += (size_t)Fn * P_;
    float* num    = ws + off; off += (size_t)S_ * Fn;
    float* alpha  = ws + off; off += (size_t)S_ * Fn;

    const int NW = S_ * Fn * C_;   // 1,982,464

    k_maps<<<(Fn * P_ + 255) / 256, 256, 0, stream>>>(lw, mw, sw, lmap, amap, sw2map, spwmap);
    k_copy<<<(NW + 255) / 256, 256, 0, stream>>>(filt, Wf, NW);

    dim3 g1((P_ + BN - 1) / BN, (Fn + BM - 1) / BM, S_);   // 8,8,16
    dim3 g2(C_ / BN, (Fn + BM - 1) / BM, S_);               // 4,8,16

    for (int it = 0; it < 3; ++it) {
        k_gemm_scores<<<g1, 256, 0, stream>>>(Wf, feat, amap, sw2map, lmap, resid, maskb);
        k_gemm_wgrad<<<g2, 256, 0, stream>>>(resid, feat, Wf, freg, wgrad);
        k_alpha_num<<<S_ * Fn, 256, 0, stream>>>(wgrad, num);
        k_gemm_sgrad<<<g1, 256, 0, stream>>>(wgrad, feat, maskb, spwmap, sg2);
        k_alpha<<<S_ * Fn, 256, 0, stream>>>(sg2, num, freg, alpha);
        k_update<<<(NW + 255) / 256, 256, 0, stream>>>(Wf, wgrad, alpha, lsl);
    }
}

// Round 2
// 278.025 us; speedup vs baseline: 2.2826x; 2.2826x over previous
//
#include <hip/hip_runtime.h>
#include <math.h>
#include <stdint.h>

#define Ww 22
#define P_ 484            // H*W (also number of filters)
#define S_ 16
#define C_ 256
#define MP2 234256        // 484*484

typedef _Float16 f16x8 __attribute__((ext_vector_type(8)));
typedef float f32x4 __attribute__((ext_vector_type(4)));

// ---- global_load_lds width-16 (CK-style addrspace cast) --------------------
__device__ __forceinline__ void gld16(const _Float16* g, _Float16* lds) {
    auto* lp = (__attribute__((address_space(3))) uint32_t*)(uintptr_t)(lds);
    auto* gp = (const __attribute__((address_space(1))) uint32_t*)(uintptr_t)(g);
    __builtin_amdgcn_global_load_lds(gp, lp, 16, 0, 0);
}

// ---------------- maps: (lab, a, sw2, spw) packed float4 --------------------
__global__ void k_maps(const float* __restrict__ label_w, const float* __restrict__ mask_w,
                       const float* __restrict__ spatial_w, f32x4* __restrict__ map4) {
    int idx = blockIdx.x * blockDim.x + threadIdx.x;
    if (idx >= MP2) return;
    int f = idx / P_, p = idx % P_;
    int i = f / Ww, j = f % Ww;
    int k = p / Ww, l = p % Ww;
    float dx = (float)(k - i), dy = (float)(l - j);
    float d = sqrtf(dx * dx + dy * dy) * 2.0f;
    float lab = 0.f, msk = 0.f, spw = 0.f;
#pragma unroll
    for (int b = 0; b < 9; ++b) {
        float wb = fmaxf(0.f, 1.f - fabsf(d - (float)b));
        lab += wb * label_w[b];
        msk += wb * mask_w[b];
        spw += wb * spatial_w[b];
    }
    float w9 = fminf(fmaxf(1.f + (d - 9.f), 0.f), 1.f);
    lab += w9 * label_w[9];
    msk += w9 * mask_w[9];
    spw += w9 * spatial_w[9];
    f32x4 o;
    o[0] = lab;
    o[1] = 1.f / (1.f + expf(-msk));
    o[2] = spw * spw;
    o[3] = spw;
    map4[idx] = o;
}

// ---------------- init: Wf = filt, Wh = f16(filt), zero num/den -------------
__global__ __launch_bounds__(256) void k_winit(const float* __restrict__ filt,
                                               float* __restrict__ Wf, _Float16* __restrict__ Wh,
                                               float* __restrict__ num, float* __restrict__ den) {
    int f = blockIdx.x, s = blockIdx.y, c = threadIdx.x;
    size_t o = ((size_t)(s * P_ + f)) * C_ + c;
    float v = filt[o];
    Wf[o] = v;
    Wh[((size_t)(s * 512 + f)) * C_ + c] = (_Float16)v;
    if (c == 0) { num[s * P_ + f] = 0.f; den[s * P_ + f] = 0.f; }
}

// ---------------- transpose+convert: f2h [s][256][512], f2th [s][512][256] --
__global__ __launch_bounds__(256) void k_trans(const float* __restrict__ feat,
                                               _Float16* __restrict__ f2h,
                                               _Float16* __restrict__ f2th) {
    int s = blockIdx.z;
    int p0 = blockIdx.x * 32, c0 = blockIdx.y * 32;
    int cc = threadIdx.x & 31, rr = threadIdx.x >> 5;  // rr 0..7
    __shared__ float tb[32][33];
#pragma unroll
    for (int q = 0; q < 4; ++q) {
        int c = c0 + rr + q * 8;
        int p = p0 + cc;
        float v = (p < P_) ? feat[((size_t)s * C_ + c) * P_ + p] : 0.f;
        f2h[((size_t)s * C_ + c) * 512 + p] = (_Float16)v;
        tb[rr + q * 8][cc] = v;
    }
    __syncthreads();
#pragma unroll
    for (int q = 0; q < 4; ++q) {
        int p = p0 + rr + q * 8;   // < 512 always, rows >=484 hold zeros
        f2th[((size_t)s * 512 + p) * C_ + c0 + cc] = (_Float16)tb[cc][rr + q * 8];
    }
}

__global__ void k_zero32(uint32_t* __restrict__ p, int n) {
    int i = blockIdx.x * blockDim.x + threadIdx.x;
    if (i < n) p[i] = 0u;
}

// ---------------- fused MFMA GEMM (NT, 128x128 tile, BK=64, 4 waves) --------
// EPI 1: scores -> residual(f16) + mask(f16)
// EPI 2: wgrad  -> wgrad(f32,+reg*W) + wgradh(f16) + atomic num
// EPI 3: sgrad  -> atomic den
template <int EPI, int LDA, int LDB, int KK>
__global__ __launch_bounds__(256) void k_gemm(
    const _Float16* __restrict__ Ah, const _Float16* __restrict__ Bh,
    const f32x4* __restrict__ map4, const _Float16* __restrict__ maskh_i,
    const float* __restrict__ Wf, const float* __restrict__ freg,
    _Float16* __restrict__ out_h, _Float16* __restrict__ out_h2,
    float* __restrict__ out_f, float* __restrict__ red) {
    int tid = threadIdx.x;
    int w = tid >> 6, l = tid & 63;
    int bid = blockIdx.x;
    int s = bid & 15;
    int t = bid >> 4;
    int m0 = (t & 3) * 128;
    int n0 = (t >> 2) * 128;
    int wm = w >> 1, wn = w & 1;

    const _Float16* Ab = Ah + (size_t)s * (512 * LDA);
    const _Float16* Bb = Bh + (size_t)s * 131072;

    __shared__ _Float16 As[8192];   // [128 rows][64 f16], granule-swizzled
    __shared__ _Float16 Bs[8192];

    // staging source addresses (granule XOR swizzle on the SOURCE side)
    int lrow = l >> 3;                       // row within 8-row chunk
    int lg = (((l & 7) ^ lrow) << 3);        // swizzled source k-granule * 8
    const _Float16* gA = Ab + (size_t)(m0 + w * 32 + lrow) * LDA + lg;
    const _Float16* gB = Bb + (size_t)(n0 + w * 32 + lrow) * LDB + lg;

    f32x4 acc[16] = {};

    for (int k0 = 0; k0 < KK; k0 += 64) {
#pragma unroll
        for (int i = 0; i < 4; ++i) {
            gld16(gA + (size_t)i * 8 * LDA + k0, As + (w * 4 + i) * 512);
            gld16(gB + (size_t)i * 8 * LDB + k0, Bs + (w * 4 + i) * 512);
        }
        __syncthreads();   // drains vmcnt -> staged data visible
#pragma unroll
        for (int kk = 0; kk < 2; ++kk) {
            int px = ((kk * 4 + (l >> 4)) ^ (l & 7)) << 3;  // swizzled read granule *8
            f16x8 af[4], bf[4];
#pragma unroll
            for (int ti = 0; ti < 4; ++ti)
                af[ti] = *(const f16x8*)(As + (wm * 64 + ti * 16 + (l & 15)) * 64 + px);
#pragma unroll
            for (int tj = 0; tj < 4; ++tj)
                bf[tj] = *(const f16x8*)(Bs + (wn * 64 + tj * 16 + (l & 15)) * 64 + px);
#pragma unroll
            for (int ti = 0; ti < 4; ++ti)
#pragma unroll
                for (int tj = 0; tj < 4; ++tj)
                    acc[ti * 4 + tj] = __builtin_amdgcn_mfma_f32_16x16x32_f16(
                        af[ti], bf[tj], acc[ti * 4 + tj], 0, 0, 0);
        }
        __syncthreads();
    }

    // ---------------- epilogue ----------------
    int r16 = l & 15;
    int q4 = (l >> 4) * 4;

    if constexpr (EPI == 1) {
#pragma unroll
        for (int ti = 0; ti < 4; ++ti) {
#pragma unroll
            for (int r = 0; r < 4; ++r) {
                int m = m0 + wm * 64 + ti * 16 + q4 + r;
                if (m < P_) {
#pragma unroll
                    for (int tj = 0; tj < 4; ++tj) {
                        int n = n0 + wn * 64 + tj * 16 + r16;
                        if (n < P_) {
                            size_t mp = (size_t)m * P_ + n;
                            f32x4 m4 = map4[mp];
                            float sc = acc[ti * 4 + tj][r];
                            float sgn = (sc > 0.f) ? 1.f : ((sc < 0.f) ? -1.f : 0.f);
                            float msk = 0.5f * (1.f - m4[1]) * sgn + 0.5f * (1.f + m4[1]);
                            float res = msk * (m4[2] * (msk * sc - m4[0]));
                            out_h[((size_t)(s * 512 + m)) * 512 + n] = (_Float16)res;
                            out_h2[(size_t)s * MP2 + mp] = (_Float16)msk;
                        }
                    }
                }
            }
        }
    } else if constexpr (EPI == 2) {
        float fr = freg[0];
        float regw = fmaxf(fr * fr, 1e-10f);
#pragma unroll
        for (int ti = 0; ti < 4; ++ti) {
#pragma unroll
            for (int r = 0; r < 4; ++r) {
                int m = m0 + wm * 64 + ti * 16 + q4 + r;
                if (m < P_) {
                    float v = 0.f;
#pragma unroll
                    for (int tj = 0; tj < 4; ++tj) {
                        int n = n0 + wn * 64 + tj * 16 + r16;   // n < 256 always
                        size_t o = ((size_t)(s * P_ + m)) * C_ + n;
                        float wg = acc[ti * 4 + tj][r] + regw * Wf[o];
                        out_f[o] = wg;
                        out_h[((size_t)(s * 512 + m)) * C_ + n] = (_Float16)wg;
                        v += wg * wg;
                    }
                    v += __shfl_xor(v, 1);
                    v += __shfl_xor(v, 2);
                    v += __shfl_xor(v, 4);
                    v += __shfl_xor(v, 8);
                    if (r16 == 0) atomicAdd(&red[s * P_ + m], v);
                }
            }
        }
    } else {
#pragma unroll
        for (int ti = 0; ti < 4; ++ti) {
#pragma unroll
            for (int r = 0; r < 4; ++r) {
                int m = m0 + wm * 64 + ti * 16 + q4 + r;
                if (m < P_) {
                    float v = 0.f;
#pragma unroll
                    for (int tj = 0; tj < 4; ++tj) {
                        int n = n0 + wn * 64 + tj * 16 + r16;
                        if (n < P_) {
                            size_t mp = (size_t)m * P_ + n;
                            float spw = map4[mp][3];
                            float msk = (float)maskh_i[(size_t)s * MP2 + mp];
                            float sg = spw * msk * acc[ti * 4 + tj][r];
                            v += sg * sg;
                        }
                    }
                    v += __shfl_xor(v, 1);
                    v += __shfl_xor(v, 2);
                    v += __shfl_xor(v, 4);
                    v += __shfl_xor(v, 8);
                    if (r16 == 0) atomicAdd(&red[s * P_ + m], v);
                }
            }
        }
    }
}

// ---------------- update: alpha + w step + f16 copy + zero reductions -------
__global__ __launch_bounds__(256) void k_update(float* __restrict__ Wf,
                                                const float* __restrict__ wgrad,
                                                float* __restrict__ num, float* __restrict__ den,
                                                const float* __restrict__ freg,
                                                const float* __restrict__ lsl,
                                                _Float16* __restrict__ Wh) {
    int f = blockIdx.x, s = blockIdx.y, c = threadIdx.x;
    int row = s * P_ + f;
    float nu = num[row], de = den[row];
    float fr = freg[0];
    float regw = fmaxf(fr * fr, 1e-10f);
    float alpha = nu / fmaxf(de + regw * nu, 1e-8f);
    float step = expf(lsl[0]);
    size_t o = (size_t)row * C_ + c;
    float wv = Wf[o] - step * alpha * wgrad[o];
    Wf[o] = wv;
    Wh[((size_t)(s * 512 + f)) * C_ + c] = (_Float16)wv;
    __syncthreads();
    if (c == 0) { num[row] = 0.f; den[row] = 0.f; }
}

// ---------------- launch -----------------------------------------------------
extern "C" void kernel_launch(void* const* d_in, const int* in_sizes, int n_in,
                              void* d_out, int out_size, void* d_ws, size_t ws_size,
                              hipStream_t stream) {
    const float* filt = (const float*)d_in[0];
    const float* feat = (const float*)d_in[1];
    const float* lsl  = (const float*)d_in[2];
    const float* freg = (const float*)d_in[3];
    const float* lw   = (const float*)d_in[4];
    const float* mw   = (const float*)d_in[5];
    const float* sw   = (const float*)d_in[6];
    float* Wf = (float*)d_out;

    // workspace carve (bytes)
    char* ws = (char*)d_ws;
    f32x4* map4   = (f32x4*)ws;                    ws += (size_t)MP2 * 16;            // 3.75 MB
    float* wgrad  = (float*)ws;                    ws += (size_t)S_ * P_ * C_ * 4;    // 7.9 MB
    float* num    = (float*)ws;                    ws += (size_t)S_ * P_ * 4;
    float* den    = (float*)ws;                    ws += (size_t)S_ * P_ * 4;
    _Float16* residh = (_Float16*)ws;              ws += (size_t)S_ * 512 * 512 * 2;  // 8.4 MB
    _Float16* f2h    = (_Float16*)ws;              ws += (size_t)S_ * C_ * 512 * 2;   // 4.2 MB
    _Float16* f2th   = (_Float16*)ws;              ws += (size_t)S_ * 512 * C_ * 2;   // 4.2 MB
    _Float16* Wh     = (_Float16*)ws;              ws += (size_t)S_ * 512 * C_ * 2;
    _Float16* wgradh = (_Float16*)ws;              ws += (size_t)S_ * 512 * C_ * 2;
    _Float16* maskh  = (_Float16*)ws;              ws += (size_t)S_ * MP2 * 2;        // 7.5 MB

    k_maps<<<(MP2 + 255) / 256, 256, 0, stream>>>(lw, mw, sw, map4);
    k_winit<<<dim3(P_, S_), 256, 0, stream>>>(filt, Wf, Wh, num, den);
    k_trans<<<dim3(16, 8, S_), 256, 0, stream>>>(feat, f2h, f2th);
    // zero residh (covers K-pad and M-tail rows), as u32
    k_zero32<<<(S_ * 512 * 512 / 2 + 255) / 256, 256, 0, stream>>>((uint32_t*)residh, S_ * 512 * 512 / 2);

    for (int it = 0; it < 3; ++it) {
        // GEMM1: scores/resid  A=Wh[512x256] B=f2th[512x256] K=256
        k_gemm<1, 256, 256, 256><<<256, 256, 0, stream>>>(
            Wh, f2th, map4, nullptr, nullptr, nullptr, residh, maskh, nullptr, nullptr);
        // GEMM2: wgrad  A=residh[512x512] B=f2h[256x512] K=512(padded)
        k_gemm<2, 512, 512, 512><<<128, 256, 0, stream>>>(
            residh, f2h, nullptr, nullptr, Wf, freg, wgradh, nullptr, wgrad, num);
        // GEMM3: sgrad->den  A=wgradh[512x256] B=f2th[512x256] K=256
        k_gemm<3, 256, 256, 256><<<256, 256, 0, stream>>>(
            wgradh, f2th, map4, maskh, nullptr, nullptr, nullptr, nullptr, nullptr, den);
        k_update<<<dim3(P_, S_), 256, 0, stream>>>(Wf, wgrad, num, den, freg, lsl, Wh);
    }
}

// Round 4
// 187.261 us; speedup vs baseline: 3.3889x; 1.4847x over previous
//
#include <hip/hip_runtime.h>
#include <math.h>
#include <stdint.h>

#define Ww 22
#define P_ 484            // H*W (also number of filters)
#define S_ 16
#define C_ 256
#define MP2 234256        // 484*484

typedef _Float16 f16x8 __attribute__((ext_vector_type(8)));
typedef _Float16 f16x4 __attribute__((ext_vector_type(4)));
typedef float f32x4 __attribute__((ext_vector_type(4)));

// ---- global_load_lds width-16 ----------------------------------------------
__device__ __forceinline__ void gld16(const _Float16* g, _Float16* lds) {
    auto* lp = (__attribute__((address_space(3))) uint32_t*)(uintptr_t)(lds);
    auto* gp = (const __attribute__((address_space(1))) uint32_t*)(uintptr_t)(g);
    __builtin_amdgcn_global_load_lds(gp, lp, 16, 0, 0);
}

// ---------------- maps: (lab, a, sw2, spw) packed float4 --------------------
__global__ void k_maps(const float* __restrict__ label_w, const float* __restrict__ mask_w,
                       const float* __restrict__ spatial_w, f32x4* __restrict__ map4) {
    int idx = blockIdx.x * blockDim.x + threadIdx.x;
    if (idx >= MP2) return;
    int f = idx / P_, p = idx % P_;
    int i = f / Ww, j = f % Ww;
    int k = p / Ww, l = p % Ww;
    float dx = (float)(k - i), dy = (float)(l - j);
    float d = sqrtf(dx * dx + dy * dy) * 2.0f;
    float lab = 0.f, msk = 0.f, spw = 0.f;
#pragma unroll
    for (int b = 0; b < 9; ++b) {
        float wb = fmaxf(0.f, 1.f - fabsf(d - (float)b));
        lab += wb * label_w[b];
        msk += wb * mask_w[b];
        spw += wb * spatial_w[b];
    }
    float w9 = fminf(fmaxf(1.f + (d - 9.f), 0.f), 1.f);
    lab += w9 * label_w[9];
    msk += w9 * mask_w[9];
    spw += w9 * spatial_w[9];
    f32x4 o;
    o[0] = lab;
    o[1] = 1.f / (1.f + expf(-msk));
    o[2] = spw * spw;
    o[3] = spw;
    map4[idx] = o;
}

__global__ void k_zero32(uint32_t* __restrict__ p, int n) {
    int i = blockIdx.x * blockDim.x + threadIdx.x;
    if (i < n) p[i] = 0u;
}

// ---------------- init: Wf = filt, Wh = f16(filt), zero num/den -------------
__global__ __launch_bounds__(256) void k_winit(const float* __restrict__ filt,
                                               float* __restrict__ Wf, _Float16* __restrict__ Wh,
                                               float* __restrict__ num, float* __restrict__ den) {
    int t = threadIdx.x;
    int f = blockIdx.x * 4 + (t >> 6);
    int s = blockIdx.y;
    int c = (t & 63) * 4;
    size_t o = ((size_t)(s * P_ + f)) * C_ + c;
    f32x4 v = *(const f32x4*)(filt + o);
    *(f32x4*)(Wf + o) = v;
    f16x4 h;
#pragma unroll
    for (int q = 0; q < 4; ++q) h[q] = (_Float16)v[q];
    *(f16x4*)(Wh + ((size_t)(s * 512 + f)) * C_ + c) = h;
    if ((t & 63) == 0) { num[s * P_ + f] = 0.f; den[s * P_ + f] = 0.f; }
}

// ---------------- transpose+convert: f2h [s][256][512], f2th [s][512][256] --
__global__ __launch_bounds__(256) void k_trans(const float* __restrict__ feat,
                                               _Float16* __restrict__ f2h,
                                               _Float16* __restrict__ f2th) {
    int s = blockIdx.z;
    int p0 = blockIdx.x * 32, c0 = blockIdx.y * 32;
    int cc = threadIdx.x & 31, rr = threadIdx.x >> 5;  // rr 0..7
    __shared__ float tb[32][33];
#pragma unroll
    for (int q = 0; q < 4; ++q) {
        int c = c0 + rr + q * 8;
        int p = p0 + cc;
        float v = (p < P_) ? feat[((size_t)s * C_ + c) * P_ + p] : 0.f;
        f2h[((size_t)s * C_ + c) * 512 + p] = (_Float16)v;
        tb[rr + q * 8][cc] = v;
    }
    __syncthreads();
#pragma unroll
    for (int q = 0; q < 4; ++q) {
        int p = p0 + rr + q * 8;   // rows >= 484 hold zeros
        f2th[((size_t)s * 512 + p) * C_ + c0 + cc] = (_Float16)tb[cc][rr + q * 8];
    }
}

// ---------------- fused MFMA GEMM, single-buffer LDS (round-2-proven loop) --
// EPI 1: scores -> residual(f16) + mask(f16)       BM=128 BN=64  K=256
// EPI 2: wgrad  -> wgradh(f16,+reg*W) + atomic num BM=64  BN=64  K=512
// EPI 3: sgrad  -> atomic den                      BM=128 BN=64  K=256
template <int EPI, int BM, int BN, int KK, int LDA, int LDB>
__global__ __launch_bounds__(256, 2) void k_gemm(
    const _Float16* __restrict__ Ah, const _Float16* __restrict__ Bh,
    const f32x4* __restrict__ map4, const _Float16* __restrict__ maskh_i,
    const _Float16* __restrict__ Wh_i, const float* __restrict__ freg,
    _Float16* __restrict__ out_h, _Float16* __restrict__ out_h2,
    float* __restrict__ red) {
    constexpr int TI = BM / 32, TJ = BN / 32, NT = KK / 64;
    int tid = threadIdx.x;
    int w = tid >> 6, l = tid & 63;
    int s = blockIdx.x;
    int m0 = blockIdx.y * BM, n0 = blockIdx.z * BN;
    int wm = w >> 1, wn = w & 1;
    int r16 = l & 15;

    __shared__ _Float16 As[BM * 64];
    __shared__ _Float16 Bs[BN * 64];

    // staging: linear LDS dest (wave base + lane*16B), source granule XOR-swizzled
    int lrow = l >> 3;
    int lg = ((l & 7) ^ lrow) << 3;
    const _Float16* gA = Ah + (size_t)s * (512 * LDA) + (size_t)(m0 + w * (BM / 4) + lrow) * LDA + lg;
    const _Float16* gB = Bh + (size_t)s * 131072 + (size_t)(n0 + w * (BN / 4) + lrow) * LDB + lg;

    f32x4 acc[TI][TJ] = {};

#pragma unroll
    for (int t = 0; t < NT; ++t) {
        // ---- stage tile t ----
#pragma unroll
        for (int i = 0; i < BM / 32; ++i)
            gld16(gA + (size_t)i * 8 * LDA + t * 64, &As[(w * (BM / 4) + i * 8) * 64]);
#pragma unroll
        for (int i = 0; i < BN / 32; ++i)
            gld16(gB + (size_t)i * 8 * LDB + t * 64, &Bs[(w * (BN / 4) + i * 8) * 64]);
        __syncthreads();   // drain vmcnt -> staged data visible to all waves
        // ---- compute tile t ----
#pragma unroll
        for (int kk = 0; kk < 2; ++kk) {
            int px = ((kk * 4 + (l >> 4)) ^ (l & 7)) << 3;  // read-side XOR swizzle
            f16x8 af[TI], bf[TJ];
#pragma unroll
            for (int ti = 0; ti < TI; ++ti)
                af[ti] = *(const f16x8*)&As[(wm * (BM / 2) + ti * 16 + r16) * 64 + px];
#pragma unroll
            for (int tj = 0; tj < TJ; ++tj)
                bf[tj] = *(const f16x8*)&Bs[(wn * (BN / 2) + tj * 16 + r16) * 64 + px];
#pragma unroll
            for (int ti = 0; ti < TI; ++ti)
#pragma unroll
                for (int tj = 0; tj < TJ; ++tj)
                    acc[ti][tj] = __builtin_amdgcn_mfma_f32_16x16x32_f16(
                        af[ti], bf[tj], acc[ti][tj], 0, 0, 0);
        }
        if (t + 1 < NT) __syncthreads();   // protect LDS reuse (write-after-read)
    }

    // ---------------- epilogue ----------------
    int q4 = (l >> 4) * 4;

    if constexpr (EPI == 1) {
#pragma unroll
        for (int ti = 0; ti < TI; ++ti)
#pragma unroll
            for (int r = 0; r < 4; ++r) {
                int m = m0 + wm * (BM / 2) + ti * 16 + q4 + r;
                if (m < P_) {
#pragma unroll
                    for (int tj = 0; tj < TJ; ++tj) {
                        int n = n0 + wn * (BN / 2) + tj * 16 + r16;
                        if (n < P_) {
                            size_t mp = (size_t)m * P_ + n;
                            f32x4 m4 = map4[mp];
                            float sc = acc[ti][tj][r];
                            float sgn = (sc > 0.f) ? 1.f : ((sc < 0.f) ? -1.f : 0.f);
                            float msk = 0.5f * (1.f - m4[1]) * sgn + 0.5f * (1.f + m4[1]);
                            float res = msk * (m4[2] * (msk * sc - m4[0]));
                            out_h[((size_t)(s * 512 + m)) * 512 + n] = (_Float16)res;
                            out_h2[(size_t)s * MP2 + mp] = (_Float16)msk;
                        }
                    }
                }
            }
    } else if constexpr (EPI == 2) {
        float fr = freg[0];
        float regw = fmaxf(fr * fr, 1e-10f);
#pragma unroll
        for (int ti = 0; ti < TI; ++ti)
#pragma unroll
            for (int r = 0; r < 4; ++r) {
                int m = m0 + wm * (BM / 2) + ti * 16 + q4 + r;
                if (m < P_) {
                    float v = 0.f;
#pragma unroll
                    for (int tj = 0; tj < TJ; ++tj) {
                        int n = n0 + wn * (BN / 2) + tj * 16 + r16;   // n < 256 always
                        size_t o = ((size_t)(s * 512 + m)) * C_ + n;
                        float wg = acc[ti][tj][r] + regw * (float)Wh_i[o];
                        out_h[o] = (_Float16)wg;
                        v += wg * wg;
                    }
                    v += __shfl_xor(v, 1);
                    v += __shfl_xor(v, 2);
                    v += __shfl_xor(v, 4);
                    v += __shfl_xor(v, 8);
                    if (r16 == 0) atomicAdd(&red[s * P_ + m], v);
                }
            }
    } else {
#pragma unroll
        for (int ti = 0; ti < TI; ++ti)
#pragma unroll
            for (int r = 0; r < 4; ++r) {
                int m = m0 + wm * (BM / 2) + ti * 16 + q4 + r;
                if (m < P_) {
                    float v = 0.f;
#pragma unroll
                    for (int tj = 0; tj < TJ; ++tj) {
                        int n = n0 + wn * (BN / 2) + tj * 16 + r16;
                        if (n < P_) {
                            size_t mp = (size_t)m * P_ + n;
                            float spw = map4[mp][3];
                            float msk = (float)maskh_i[(size_t)s * MP2 + mp];
                            float sg = spw * msk * acc[ti][tj][r];
                            v += sg * sg;
                        }
                    }
                    v += __shfl_xor(v, 1);
                    v += __shfl_xor(v, 2);
                    v += __shfl_xor(v, 4);
                    v += __shfl_xor(v, 8);
                    if (r16 == 0) atomicAdd(&red[s * P_ + m], v);
                }
            }
    }
}

// ---------------- update: alpha + w step + f16 copy + zero reductions -------
__global__ __launch_bounds__(256) void k_update(float* __restrict__ Wf,
                                                const _Float16* __restrict__ wgradh,
                                                float* __restrict__ num, float* __restrict__ den,
                                                const float* __restrict__ freg,
                                                const float* __restrict__ lsl,
                                                _Float16* __restrict__ Wh) {
    int t = threadIdx.x;
    int f = blockIdx.x * 4 + (t >> 6);
    int s = blockIdx.y;
    int row = s * P_ + f;
    float nu = num[row], de = den[row];
    float fr = freg[0];
    float regw = fmaxf(fr * fr, 1e-10f);
    float alpha = nu / fmaxf(de + regw * nu, 1e-8f);
    float sa = expf(lsl[0]) * alpha;
    int c = (t & 63) * 4;
    size_t o = (size_t)row * C_ + c;
    size_t oh = ((size_t)(s * 512 + f)) * C_ + c;
    f32x4 wv = *(const f32x4*)(Wf + o);
    f16x4 g = *(const f16x4*)(wgradh + oh);
    f16x4 h;
#pragma unroll
    for (int q = 0; q < 4; ++q) {
        wv[q] -= sa * (float)g[q];
        h[q] = (_Float16)wv[q];
    }
    *(f32x4*)(Wf + o) = wv;
    *(f16x4*)(Wh + oh) = h;
    if ((t & 63) == 0) { num[row] = 0.f; den[row] = 0.f; }
}

// ---------------- launch -----------------------------------------------------
extern "C" void kernel_launch(void* const* d_in, const int* in_sizes, int n_in,
                              void* d_out, int out_size, void* d_ws, size_t ws_size,
                              hipStream_t stream) {
    const float* filt = (const float*)d_in[0];
    const float* feat = (const float*)d_in[1];
    const float* lsl  = (const float*)d_in[2];
    const float* freg = (const float*)d_in[3];
    const float* lw   = (const float*)d_in[4];
    const float* mw   = (const float*)d_in[5];
    const float* sw   = (const float*)d_in[6];
    float* Wf = (float*)d_out;

    // workspace carve (bytes); residh/wgradh/Wh contiguous for one zero pass
    char* ws = (char*)d_ws;
    f32x4* map4      = (f32x4*)ws;      ws += (size_t)MP2 * 16;            // 3.75 MB
    _Float16* residh = (_Float16*)ws;   ws += (size_t)S_ * 512 * 512 * 2;  // 8.4 MB
    _Float16* wgradh = (_Float16*)ws;   ws += (size_t)S_ * 512 * C_ * 2;   // 4.2 MB
    _Float16* Wh     = (_Float16*)ws;   ws += (size_t)S_ * 512 * C_ * 2;   // 4.2 MB
    _Float16* f2h    = (_Float16*)ws;   ws += (size_t)S_ * C_ * 512 * 2;   // 4.2 MB
    _Float16* f2th   = (_Float16*)ws;   ws += (size_t)S_ * 512 * C_ * 2;   // 4.2 MB
    _Float16* maskh  = (_Float16*)ws;   ws += (size_t)S_ * MP2 * 2;        // 7.5 MB
    float* num       = (float*)ws;      ws += (size_t)S_ * P_ * 4;
    float* den       = (float*)ws;      ws += (size_t)S_ * P_ * 4;

    // zero residh+wgradh+Wh (16 MB contiguous) -> covers all pad rows/cols
    const int NZ = (int)(((size_t)S_ * 512 * 512 + 2 * (size_t)S_ * 512 * C_) * 2 / 4);
    k_zero32<<<(NZ + 255) / 256, 256, 0, stream>>>((uint32_t*)residh, NZ);
    k_maps<<<(MP2 + 255) / 256, 256, 0, stream>>>(lw, mw, sw, map4);
    k_winit<<<dim3(121, S_), 256, 0, stream>>>(filt, Wf, Wh, num, den);
    k_trans<<<dim3(16, 8, S_), 256, 0, stream>>>(feat, f2h, f2th);

    for (int it = 0; it < 3; ++it) {
        // GEMM1: A=Wh [512x256], B=f2th [512x256], K=256 -> residh/maskh
        k_gemm<1, 128, 64, 256, 256, 256><<<dim3(16, 4, 8), 256, 0, stream>>>(
            Wh, f2th, map4, nullptr, nullptr, nullptr, residh, maskh, nullptr);
        // GEMM2: A=residh [512x512], B=f2h [256x512], K=512 -> wgradh + num
        k_gemm<2, 64, 64, 512, 512, 512><<<dim3(16, 8, 4), 256, 0, stream>>>(
            residh, f2h, nullptr, nullptr, Wh, freg, wgradh, nullptr, num);
        // GEMM3: A=wgradh [512x256], B=f2th [512x256], K=256 -> den
        k_gemm<3, 128, 64, 256, 256, 256><<<dim3(16, 4, 8), 256, 0, stream>>>(
            wgradh, f2th, map4, maskh, nullptr, nullptr, nullptr, nullptr, den);
        k_update<<<dim3(121, S_), 256, 0, stream>>>(Wf, wgradh, num, den, freg, lsl, Wh);
    }
}

// Round 5
// 150.415 us; speedup vs baseline: 4.2191x; 1.2450x over previous
//
#include <hip/hip_runtime.h>
#include <math.h>
#include <stdint.h>

#define Ww 22
#define P_ 484            // H*W (also number of filters)
#define S_ 16
#define C_ 256
#define MP2 234256        // 484*484
#define TSZ 1849          // 43*43 distance table

typedef _Float16 f16x8 __attribute__((ext_vector_type(8)));
typedef _Float16 f16x4 __attribute__((ext_vector_type(4)));
typedef float f32x4 __attribute__((ext_vector_type(4)));

// ---- global_load_lds width-16 ----------------------------------------------
__device__ __forceinline__ void gld16(const _Float16* g, _Float16* lds) {
    auto* lp = (__attribute__((address_space(3))) uint32_t*)(uintptr_t)(lds);
    auto* gp = (const __attribute__((address_space(1))) uint32_t*)(uintptr_t)(g);
    __builtin_amdgcn_global_load_lds(gp, lp, 16, 0, 0);
}

// ---------------- maps table: 43x43 entries of (lab, a, sw2, spw) -----------
__global__ void k_maps(const float* __restrict__ label_w, const float* __restrict__ mask_w,
                       const float* __restrict__ spatial_w, f32x4* __restrict__ map4t) {
    int idx = blockIdx.x * blockDim.x + threadIdx.x;
    if (idx >= TSZ) return;
    int dx = idx / 43 - 21, dy = idx % 43 - 21;
    float d = sqrtf((float)(dx * dx + dy * dy)) * 2.0f;
    float lab = 0.f, msk = 0.f, spw = 0.f;
#pragma unroll
    for (int b = 0; b < 9; ++b) {
        float wb = fmaxf(0.f, 1.f - fabsf(d - (float)b));
        lab += wb * label_w[b];
        msk += wb * mask_w[b];
        spw += wb * spatial_w[b];
    }
    float w9 = fminf(fmaxf(1.f + (d - 9.f), 0.f), 1.f);
    lab += w9 * label_w[9];
    msk += w9 * mask_w[9];
    spw += w9 * spatial_w[9];
    f32x4 o;
    o[0] = lab;
    o[1] = 1.f / (1.f + expf(-msk));
    o[2] = spw * spw;
    o[3] = spw;
    map4t[idx] = o;
}

// ---------------- init: Wf = filt, Wh = f16(filt) (+zero pad rows) ----------
__global__ __launch_bounds__(256) void k_winit(const float* __restrict__ filt,
                                               float* __restrict__ Wf, _Float16* __restrict__ Wh,
                                               float* __restrict__ num, float* __restrict__ den) {
    int t = threadIdx.x;
    int f = blockIdx.x * 4 + (t >> 6);   // 0..511
    int s = blockIdx.y;
    int c = (t & 63) * 4;
    size_t oh = ((size_t)(s * 512 + f)) * C_ + c;
    if (f < P_) {
        size_t o = ((size_t)(s * P_ + f)) * C_ + c;
        f32x4 v = *(const f32x4*)(filt + o);
        *(f32x4*)(Wf + o) = v;
        f16x4 h;
#pragma unroll
        for (int q = 0; q < 4; ++q) h[q] = (_Float16)v[q];
        *(f16x4*)(Wh + oh) = h;
        if ((t & 63) == 0) { num[s * P_ + f] = 0.f; den[s * P_ + f] = 0.f; }
    } else {
        f16x4 h = {};
        *(f16x4*)(Wh + oh) = h;   // zero pad rows (A-operand of GEMM1)
    }
}

// ---------------- transpose+convert: f2h [s][256][512], f2th [s][512][256] --
__global__ __launch_bounds__(256) void k_trans(const float* __restrict__ feat,
                                               _Float16* __restrict__ f2h,
                                               _Float16* __restrict__ f2th) {
    int s = blockIdx.z;
    int p0 = blockIdx.x * 32, c0 = blockIdx.y * 32;
    int cc = threadIdx.x & 31, rr = threadIdx.x >> 5;  // rr 0..7
    __shared__ float tb[32][33];
#pragma unroll
    for (int q = 0; q < 4; ++q) {
        int c = c0 + rr + q * 8;
        int p = p0 + cc;
        float v = (p < P_) ? feat[((size_t)s * C_ + c) * P_ + p] : 0.f;
        f2h[((size_t)s * C_ + c) * 512 + p] = (_Float16)v;
        tb[rr + q * 8][cc] = v;
    }
    __syncthreads();
#pragma unroll
    for (int q = 0; q < 4; ++q) {
        int p = p0 + rr + q * 8;   // rows >= 484 hold zeros
        f2th[((size_t)s * 512 + p) * C_ + c0 + cc] = (_Float16)tb[cc][rr + q * 8];
    }
}

// ---------------- fused MFMA GEMM, single-buffer LDS (round-4-proven loop) --
// 64x64 tiles, 4 waves, TI=TJ=2.
// EPI 1: scores -> residual(f16, pads zeroed) + mask(f16)   K=256, grid 16x8x8
// EPI 2: wgrad  -> wgradh(f16,+reg*W) + atomic num          K=512, grid 16x8x4
// EPI 3: sgrad  -> atomic den                               K=256, grid 16x8x8
template <int EPI, int KK, int LDA, int LDB>
__global__ __launch_bounds__(256, 4) void k_gemm(
    const _Float16* __restrict__ Ah, const _Float16* __restrict__ Bh,
    const f32x4* __restrict__ map4t, const _Float16* __restrict__ maskh_i,
    const _Float16* __restrict__ Wh_i, const float* __restrict__ freg,
    _Float16* __restrict__ out_h, _Float16* __restrict__ out_h2,
    float* __restrict__ red) {
    constexpr int BM = 64, BN = 64;
    constexpr int TI = 2, TJ = 2, NT = KK / 64;
    int tid = threadIdx.x;
    int w = tid >> 6, l = tid & 63;
    int s = blockIdx.x;
    int m0 = blockIdx.y * BM, n0 = blockIdx.z * BN;
    int wm = w >> 1, wn = w & 1;
    int r16 = l & 15;

    __shared__ _Float16 As[BM * 64];
    __shared__ _Float16 Bs[BN * 64];

    // staging: linear LDS dest (wave base + lane*16B), source granule XOR-swizzled
    int lrow = l >> 3;
    int lg = ((l & 7) ^ lrow) << 3;
    const _Float16* gA = Ah + (size_t)s * (512 * LDA) + (size_t)(m0 + w * 16 + lrow) * LDA + lg;
    const _Float16* gB = Bh + (size_t)s * 131072 + (size_t)(n0 + w * 16 + lrow) * LDB + lg;

    f32x4 acc[TI][TJ] = {};

#pragma unroll
    for (int t = 0; t < NT; ++t) {
        // ---- stage tile t ----
#pragma unroll
        for (int i = 0; i < 2; ++i) {
            gld16(gA + (size_t)i * 8 * LDA + t * 64, &As[(w * 16 + i * 8) * 64]);
            gld16(gB + (size_t)i * 8 * LDB + t * 64, &Bs[(w * 16 + i * 8) * 64]);
        }
        __syncthreads();   // drain vmcnt -> staged data visible to all waves
        // ---- compute tile t ----
#pragma unroll
        for (int kk = 0; kk < 2; ++kk) {
            int px = ((kk * 4 + (l >> 4)) ^ (l & 7)) << 3;  // read-side XOR swizzle
            f16x8 af[TI], bf[TJ];
#pragma unroll
            for (int ti = 0; ti < TI; ++ti)
                af[ti] = *(const f16x8*)&As[(wm * 32 + ti * 16 + r16) * 64 + px];
#pragma unroll
            for (int tj = 0; tj < TJ; ++tj)
                bf[tj] = *(const f16x8*)&Bs[(wn * 32 + tj * 16 + r16) * 64 + px];
#pragma unroll
            for (int ti = 0; ti < TI; ++ti)
#pragma unroll
                for (int tj = 0; tj < TJ; ++tj)
                    acc[ti][tj] = __builtin_amdgcn_mfma_f32_16x16x32_f16(
                        af[ti], bf[tj], acc[ti][tj], 0, 0, 0);
        }
        if (t + 1 < NT) __syncthreads();   // protect LDS reuse (write-after-read)
    }

    // ---------------- epilogue ----------------
    int q4 = (l >> 4) * 4;

    if constexpr (EPI == 1) {
#pragma unroll
        for (int ti = 0; ti < TI; ++ti)
#pragma unroll
            for (int r = 0; r < 4; ++r) {
                int m = m0 + wm * 32 + ti * 16 + q4 + r;
                int im = m / 22, jm = m - im * 22;
#pragma unroll
                for (int tj = 0; tj < TJ; ++tj) {
                    int n = n0 + wn * 32 + tj * 16 + r16;
                    float res = 0.f;
                    if (m < P_ && n < P_) {
                        int kn = n / 22, ln = n - kn * 22;
                        f32x4 m4 = map4t[(kn - im + 21) * 43 + (ln - jm + 21)];
                        float sc = acc[ti][tj][r];
                        float sgn = (sc > 0.f) ? 1.f : ((sc < 0.f) ? -1.f : 0.f);
                        float msk = 0.5f * (1.f - m4[1]) * sgn + 0.5f * (1.f + m4[1]);
                        res = msk * (m4[2] * (msk * sc - m4[0]));
                        out_h2[(size_t)s * MP2 + (size_t)m * P_ + n] = (_Float16)msk;
                    }
                    out_h[((size_t)(s * 512 + m)) * 512 + n] = (_Float16)res;  // pads -> 0
                }
            }
    } else if constexpr (EPI == 2) {
        float fr = freg[0];
        float regw = fmaxf(fr * fr, 1e-10f);
#pragma unroll
        for (int ti = 0; ti < TI; ++ti)
#pragma unroll
            for (int r = 0; r < 4; ++r) {
                int m = m0 + wm * 32 + ti * 16 + q4 + r;
                float v = 0.f;
#pragma unroll
                for (int tj = 0; tj < TJ; ++tj) {
                    int n = n0 + wn * 32 + tj * 16 + r16;   // n < 256 always
                    size_t o = ((size_t)(s * 512 + m)) * C_ + n;
                    // pad rows: acc==0 and Wh==0 -> wg==0 (keeps wgradh pads zero)
                    float wg = acc[ti][tj][r] + regw * (float)Wh_i[o];
                    out_h[o] = (_Float16)wg;
                    v += wg * wg;
                }
                v += __shfl_xor(v, 1);
                v += __shfl_xor(v, 2);
                v += __shfl_xor(v, 4);
                v += __shfl_xor(v, 8);
                if (r16 == 0 && m < P_) atomicAdd(&red[s * P_ + m], v);
            }
    } else {
#pragma unroll
        for (int ti = 0; ti < TI; ++ti)
#pragma unroll
            for (int r = 0; r < 4; ++r) {
                int m = m0 + wm * 32 + ti * 16 + q4 + r;
                int im = m / 22, jm = m - im * 22;
                float v = 0.f;
#pragma unroll
                for (int tj = 0; tj < TJ; ++tj) {
                    int n = n0 + wn * 32 + tj * 16 + r16;
                    if (m < P_ && n < P_) {
                        int kn = n / 22, ln = n - kn * 22;
                        float spw = map4t[(kn - im + 21) * 43 + (ln - jm + 21)][3];
                        float msk = (float)maskh_i[(size_t)s * MP2 + (size_t)m * P_ + n];
                        float sg = spw * msk * acc[ti][tj][r];
                        v += sg * sg;
                    }
                }
                v += __shfl_xor(v, 1);
                v += __shfl_xor(v, 2);
                v += __shfl_xor(v, 4);
                v += __shfl_xor(v, 8);
                if (r16 == 0 && m < P_) atomicAdd(&red[s * P_ + m], v);
            }
    }
}

// ---------------- update: alpha + w step + f16 copy + zero reductions -------
__global__ __launch_bounds__(256) void k_update(float* __restrict__ Wf,
                                                const _Float16* __restrict__ wgradh,
                                                float* __restrict__ num, float* __restrict__ den,
                                                const float* __restrict__ freg,
                                                const float* __restrict__ lsl,
                                                _Float16* __restrict__ Wh) {
    int t = threadIdx.x;
    int f = blockIdx.x * 4 + (t >> 6);
    int s = blockIdx.y;
    int row = s * P_ + f;
    float nu = num[row], de = den[row];
    float fr = freg[0];
    float regw = fmaxf(fr * fr, 1e-10f);
    float alpha = nu / fmaxf(de + regw * nu, 1e-8f);
    float sa = expf(lsl[0]) * alpha;
    int c = (t & 63) * 4;
    size_t o = (size_t)row * C_ + c;
    size_t oh = ((size_t)(s * 512 + f)) * C_ + c;
    f32x4 wv = *(const f32x4*)(Wf + o);
    f16x4 g = *(const f16x4*)(wgradh + oh);
    f16x4 h;
#pragma unroll
    for (int q = 0; q < 4; ++q) {
        wv[q] -= sa * (float)g[q];
        h[q] = (_Float16)wv[q];
    }
    *(f32x4*)(Wf + o) = wv;
    *(f16x4*)(Wh + oh) = h;
    if ((t & 63) == 0) { num[row] = 0.f; den[row] = 0.f; }
}

// ---------------- launch -----------------------------------------------------
extern "C" void kernel_launch(void* const* d_in, const int* in_sizes, int n_in,
                              void* d_out, int out_size, void* d_ws, size_t ws_size,
                              hipStream_t stream) {
    const float* filt = (const float*)d_in[0];
    const float* feat = (const float*)d_in[1];
    const float* lsl  = (const float*)d_in[2];
    const float* freg = (const float*)d_in[3];
    const float* lw   = (const float*)d_in[4];
    const float* mw   = (const float*)d_in[5];
    const float* sw   = (const float*)d_in[6];
    float* Wf = (float*)d_out;

    // workspace carve (bytes)
    char* ws = (char*)d_ws;
    f32x4* map4t     = (f32x4*)ws;      ws += (size_t)TSZ * 16;            // 29.6 KB
    _Float16* residh = (_Float16*)ws;   ws += (size_t)S_ * 512 * 512 * 2;  // 8.4 MB
    _Float16* wgradh = (_Float16*)ws;   ws += (size_t)S_ * 512 * C_ * 2;   // 4.2 MB
    _Float16* Wh     = (_Float16*)ws;   ws += (size_t)S_ * 512 * C_ * 2;   // 4.2 MB
    _Float16* f2h    = (_Float16*)ws;   ws += (size_t)S_ * C_ * 512 * 2;   // 4.2 MB
    _Float16* f2th   = (_Float16*)ws;   ws += (size_t)S_ * 512 * C_ * 2;   // 4.2 MB
    _Float16* maskh  = (_Float16*)ws;   ws += (size_t)S_ * MP2 * 2;        // 7.5 MB
    float* num       = (float*)ws;      ws += (size_t)S_ * P_ * 4;
    float* den       = (float*)ws;      ws += (size_t)S_ * P_ * 4;

    k_maps<<<8, 256, 0, stream>>>(lw, mw, sw, map4t);
    k_winit<<<dim3(128, S_), 256, 0, stream>>>(filt, Wf, Wh, num, den);
    k_trans<<<dim3(16, 8, S_), 256, 0, stream>>>(feat, f2h, f2th);

    for (int it = 0; it < 3; ++it) {
        // GEMM1: A=Wh [512x256], B=f2th [512x256], K=256 -> residh(all)/maskh
        k_gemm<1, 256, 256, 256><<<dim3(16, 8, 8), 256, 0, stream>>>(
            Wh, f2th, map4t, nullptr, nullptr, nullptr, residh, maskh, nullptr);
        // GEMM2: A=residh [512x512], B=f2h [256x512], K=512 -> wgradh + num
        k_gemm<2, 512, 512, 512><<<dim3(16, 8, 4), 256, 0, stream>>>(
            residh, f2h, map4t, nullptr, Wh, freg, wgradh, nullptr, num);
        // GEMM3: A=wgradh [512x256], B=f2th [512x256], K=256 -> den
        k_gemm<3, 256, 256, 256><<<dim3(16, 8, 8), 256, 0, stream>>>(
            wgradh, f2th, map4t, maskh, nullptr, nullptr, nullptr, nullptr, den);
        k_update<<<dim3(121, S_), 256, 0, stream>>>(Wf, wgradh, num, den, freg, lsl, Wh);
    }
}

// Round 6
// 146.456 us; speedup vs baseline: 4.3331x; 1.0270x over previous
//
#include <hip/hip_runtime.h>
#include <math.h>
#include <stdint.h>

#define Ww 22
#define P_ 484            // H*W (also number of filters)
#define S_ 16
#define C_ 256
#define MP2 234256        // 484*484
#define TSZ 1849          // 43*43 distance table

typedef _Float16 f16x8 __attribute__((ext_vector_type(8)));
typedef _Float16 f16x4 __attribute__((ext_vector_type(4)));
typedef float f32x4 __attribute__((ext_vector_type(4)));

// ---- global_load_lds width-16 ----------------------------------------------
__device__ __forceinline__ void gld16(const _Float16* g, _Float16* lds) {
    auto* lp = (__attribute__((address_space(3))) uint32_t*)(uintptr_t)(lds);
    auto* gp = (const __attribute__((address_space(1))) uint32_t*)(uintptr_t)(g);
    __builtin_amdgcn_global_load_lds(gp, lp, 16, 0, 0);
}

// ---------------- maps table: 43x43 entries of (lab, a, sw2, spw) -----------
__global__ void k_maps(const float* __restrict__ label_w, const float* __restrict__ mask_w,
                       const float* __restrict__ spatial_w, f32x4* __restrict__ map4t) {
    int idx = blockIdx.x * blockDim.x + threadIdx.x;
    if (idx >= TSZ) return;
    int dx = idx / 43 - 21, dy = idx % 43 - 21;
    float d = sqrtf((float)(dx * dx + dy * dy)) * 2.0f;
    float lab = 0.f, msk = 0.f, spw = 0.f;
#pragma unroll
    for (int b = 0; b < 9; ++b) {
        float wb = fmaxf(0.f, 1.f - fabsf(d - (float)b));
        lab += wb * label_w[b];
        msk += wb * mask_w[b];
        spw += wb * spatial_w[b];
    }
    float w9 = fminf(fmaxf(1.f + (d - 9.f), 0.f), 1.f);
    lab += w9 * label_w[9];
    msk += w9 * mask_w[9];
    spw += w9 * spatial_w[9];
    f32x4 o;
    o[0] = lab;
    o[1] = 1.f / (1.f + expf(-msk));
    o[2] = spw * spw;
    o[3] = spw;
    map4t[idx] = o;
}

// ---------------- init: Wf = filt, Wh = f16(filt) (+zero pad rows) ----------
__global__ __launch_bounds__(256) void k_winit(const float* __restrict__ filt,
                                               float* __restrict__ Wf, _Float16* __restrict__ Wh,
                                               float* __restrict__ num, float* __restrict__ den) {
    int t = threadIdx.x;
    int f = blockIdx.x * 4 + (t >> 6);   // 0..511
    int s = blockIdx.y;
    int c = (t & 63) * 4;
    size_t oh = ((size_t)(s * 512 + f)) * C_ + c;
    if (f < P_) {
        size_t o = ((size_t)(s * P_ + f)) * C_ + c;
        f32x4 v = *(const f32x4*)(filt + o);
        *(f32x4*)(Wf + o) = v;
        f16x4 h;
#pragma unroll
        for (int q = 0; q < 4; ++q) h[q] = (_Float16)v[q];
        *(f16x4*)(Wh + oh) = h;
        if ((t & 63) == 0) { num[s * P_ + f] = 0.f; den[s * P_ + f] = 0.f; }
    } else {
        f16x4 h = {};
        *(f16x4*)(Wh + oh) = h;   // zero pad rows (A-operand of GEMM1)
    }
}

// ---------------- transpose+convert: f2h [s][256][512], f2th [s][512][256] --
__global__ __launch_bounds__(256) void k_trans(const float* __restrict__ feat,
                                               _Float16* __restrict__ f2h,
                                               _Float16* __restrict__ f2th) {
    int s = blockIdx.z;
    int p0 = blockIdx.x * 32, c0 = blockIdx.y * 32;
    int cc = threadIdx.x & 31, rr = threadIdx.x >> 5;  // rr 0..7
    __shared__ float tb[32][33];
#pragma unroll
    for (int q = 0; q < 4; ++q) {
        int c = c0 + rr + q * 8;
        int p = p0 + cc;
        float v = (p < P_) ? feat[((size_t)s * C_ + c) * P_ + p] : 0.f;
        f2h[((size_t)s * C_ + c) * 512 + p] = (_Float16)v;
        tb[rr + q * 8][cc] = v;
    }
    __syncthreads();
#pragma unroll
    for (int q = 0; q < 4; ++q) {
        int p = p0 + rr + q * 8;   // rows >= 484 hold zeros
        f2th[((size_t)s * 512 + p) * C_ + c0 + cc] = (_Float16)tb[cc][rr + q * 8];
    }
}

// ---------------- fused MFMA GEMM, single-buffer LDS, BK=128 per barrier ----
// 64x64 tiles, 4 waves, TI=TJ=2; same proven stage->sync->compute->sync loop,
// half the barrier rounds of round 5 (NT = K/128).
// EPI 1: scores -> residual(f16, pads zeroed) + mask(f16)   K=256, grid 16x8x8
// EPI 2: wgrad  -> wgradh(f16,+reg*W) + atomic num          K=512, grid 16x8x4
// EPI 3: sgrad  -> atomic den                               K=256, grid 16x8x8
template <int EPI, int KK, int LDA, int LDB>
__global__ __launch_bounds__(256, 4) void k_gemm(
    const _Float16* __restrict__ Ah, const _Float16* __restrict__ Bh,
    const f32x4* __restrict__ map4t, const _Float16* __restrict__ maskh_i,
    const _Float16* __restrict__ Wh_i, const float* __restrict__ freg,
    _Float16* __restrict__ out_h, _Float16* __restrict__ out_h2,
    float* __restrict__ red) {
    constexpr int TI = 2, TJ = 2, NT = KK / 128;
    int tid = threadIdx.x;
    int w = tid >> 6, l = tid & 63;
    int s = blockIdx.x;
    int m0 = blockIdx.y * 64, n0 = blockIdx.z * 64;
    int wm = w >> 1, wn = w & 1;
    int r16 = l & 15;

    __shared__ _Float16 As[64 * 128];   // 16 KB
    __shared__ _Float16 Bs[64 * 128];   // 16 KB

    // staging: linear LDS dest (wave-uniform base + lane*16B).
    // invariant: LDS[row][g] = global[row][g ^ (row & 15)]  (16B granules)
    int lrow = w * 4 + (l >> 4);               // row & 15 for every issue (chunk stride 16)
    int gsrc = ((l & 15) ^ lrow) << 3;         // swizzled source granule, f16 units
    const _Float16* gA = Ah + (size_t)s * (512 * LDA) + (size_t)(m0 + lrow) * LDA + gsrc;
    const _Float16* gB = Bh + (size_t)s * 131072 + (size_t)(n0 + lrow) * LDB + gsrc;

    f32x4 acc[TI][TJ] = {};

#pragma unroll
    for (int t = 0; t < NT; ++t) {
        // ---- stage K-chunk t (128 wide): 4 issues/wave per operand ----
#pragma unroll
        for (int i = 0; i < 4; ++i) {
            gld16(gA + (size_t)i * 16 * LDA + t * 128, &As[(i * 16 + w * 4) * 128]);
            gld16(gB + (size_t)i * 16 * LDB + t * 128, &Bs[(i * 16 + w * 4) * 128]);
        }
        __syncthreads();   // drain vmcnt -> staged data visible to all waves
        // ---- compute: 4 MFMA k-slices of 32 ----
#pragma unroll
        for (int kk = 0; kk < 4; ++kk) {
            int px = ((kk * 4 + (l >> 4)) ^ r16) << 3;  // read-side XOR swizzle
            f16x8 af[TI], bf[TJ];
#pragma unroll
            for (int ti = 0; ti < TI; ++ti)
                af[ti] = *(const f16x8*)&As[(wm * 32 + ti * 16 + r16) * 128 + px];
#pragma unroll
            for (int tj = 0; tj < TJ; ++tj)
                bf[tj] = *(const f16x8*)&Bs[(wn * 32 + tj * 16 + r16) * 128 + px];
#pragma unroll
            for (int ti = 0; ti < TI; ++ti)
#pragma unroll
                for (int tj = 0; tj < TJ; ++tj)
                    acc[ti][tj] = __builtin_amdgcn_mfma_f32_16x16x32_f16(
                        af[ti], bf[tj], acc[ti][tj], 0, 0, 0);
        }
        if (t + 1 < NT) __syncthreads();   // protect LDS reuse (write-after-read)
    }

    // ---------------- epilogue ----------------
    int q4 = (l >> 4) * 4;

    if constexpr (EPI == 1) {
#pragma unroll
        for (int ti = 0; ti < TI; ++ti)
#pragma unroll
            for (int r = 0; r < 4; ++r) {
                int m = m0 + wm * 32 + ti * 16 + q4 + r;
                int im = m / 22, jm = m - im * 22;
#pragma unroll
                for (int tj = 0; tj < TJ; ++tj) {
                    int n = n0 + wn * 32 + tj * 16 + r16;
                    float res = 0.f;
                    if (m < P_ && n < P_) {
                        int kn = n / 22, ln = n - kn * 22;
                        f32x4 m4 = map4t[(kn - im + 21) * 43 + (ln - jm + 21)];
                        float sc = acc[ti][tj][r];
                        float sgn = (sc > 0.f) ? 1.f : ((sc < 0.f) ? -1.f : 0.f);
                        float msk = 0.5f * (1.f - m4[1]) * sgn + 0.5f * (1.f + m4[1]);
                        res = msk * (m4[2] * (msk * sc - m4[0]));
                        out_h2[(size_t)s * MP2 + (size_t)m * P_ + n] = (_Float16)msk;
                    }
                    out_h[((size_t)(s * 512 + m)) * 512 + n] = (_Float16)res;  // pads -> 0
                }
            }
    } else if constexpr (EPI == 2) {
        float fr = freg[0];
        float regw = fmaxf(fr * fr, 1e-10f);
#pragma unroll
        for (int ti = 0; ti < TI; ++ti)
#pragma unroll
            for (int r = 0; r < 4; ++r) {
                int m = m0 + wm * 32 + ti * 16 + q4 + r;
                float v = 0.f;
#pragma unroll
                for (int tj = 0; tj < TJ; ++tj) {
                    int n = n0 + wn * 32 + tj * 16 + r16;   // n < 256 always
                    size_t o = ((size_t)(s * 512 + m)) * C_ + n;
                    // pad rows: acc==0 and Wh==0 -> wg==0 (keeps wgradh pads zero)
                    float wg = acc[ti][tj][r] + regw * (float)Wh_i[o];
                    out_h[o] = (_Float16)wg;
                    v += wg * wg;
                }
                v += __shfl_xor(v, 1);
                v += __shfl_xor(v, 2);
                v += __shfl_xor(v, 4);
                v += __shfl_xor(v, 8);
                if (r16 == 0 && m < P_) atomicAdd(&red[s * P_ + m], v);
            }
    } else {
#pragma unroll
        for (int ti = 0; ti < TI; ++ti)
#pragma unroll
            for (int r = 0; r < 4; ++r) {
                int m = m0 + wm * 32 + ti * 16 + q4 + r;
                int im = m / 22, jm = m - im * 22;
                float v = 0.f;
#pragma unroll
                for (int tj = 0; tj < TJ; ++tj) {
                    int n = n0 + wn * 32 + tj * 16 + r16;
                    if (m < P_ && n < P_) {
                        int kn = n / 22, ln = n - kn * 22;
                        float spw = map4t[(kn - im + 21) * 43 + (ln - jm + 21)][3];
                        float msk = (float)maskh_i[(size_t)s * MP2 + (size_t)m * P_ + n];
                        float sg = spw * msk * acc[ti][tj][r];
                        v += sg * sg;
                    }
                }
                v += __shfl_xor(v, 1);
                v += __shfl_xor(v, 2);
                v += __shfl_xor(v, 4);
                v += __shfl_xor(v, 8);
                if (r16 == 0 && m < P_) atomicAdd(&red[s * P_ + m], v);
            }
    }
}

// ---------------- update: alpha + w step + f16 copy + zero reductions -------
__global__ __launch_bounds__(256) void k_update(float* __restrict__ Wf,
                                                const _Float16* __restrict__ wgradh,
                                                float* __restrict__ num, float* __restrict__ den,
                                                const float* __restrict__ freg,
                                                const float* __restrict__ lsl,
                                                _Float16* __restrict__ Wh) {
    int t = threadIdx.x;
    int f = blockIdx.x * 4 + (t >> 6);
    int s = blockIdx.y;
    int row = s * P_ + f;
    float nu = num[row], de = den[row];
    float fr = freg[0];
    float regw = fmaxf(fr * fr, 1e-10f);
    float alpha = nu / fmaxf(de + regw * nu, 1e-8f);
    float sa = expf(lsl[0]) * alpha;
    int c = (t & 63) * 4;
    size_t o = (size_t)row * C_ + c;
    size_t oh = ((size_t)(s * 512 + f)) * C_ + c;
    f32x4 wv = *(const f32x4*)(Wf + o);
    f16x4 g = *(const f16x4*)(wgradh + oh);
    f16x4 h;
#pragma unroll
    for (int q = 0; q < 4; ++q) {
        wv[q] -= sa * (float)g[q];
        h[q] = (_Float16)wv[q];
    }
    *(f32x4*)(Wf + o) = wv;
    *(f16x4*)(Wh + oh) = h;
    if ((t & 63) == 0) { num[row] = 0.f; den[row] = 0.f; }
}

// ---------------- launch -----------------------------------------------------
extern "C" void kernel_launch(void* const* d_in, const int* in_sizes, int n_in,
                              void* d_out, int out_size, void* d_ws, size_t ws_size,
                              hipStream_t stream) {
    const float* filt = (const float*)d_in[0];
    const float* feat = (const float*)d_in[1];
    const float* lsl  = (const float*)d_in[2];
    const float* freg = (const float*)d_in[3];
    const float* lw   = (const float*)d_in[4];
    const float* mw   = (const float*)d_in[5];
    const float* sw   = (const float*)d_in[6];
    float* Wf = (float*)d_out;

    // workspace carve (bytes)
    char* ws = (char*)d_ws;
    f32x4* map4t     = (f32x4*)ws;      ws += (size_t)TSZ * 16;            // 29.6 KB
    _Float16* residh = (_Float16*)ws;   ws += (size_t)S_ * 512 * 512 * 2;  // 8.4 MB
    _Float16* wgradh = (_Float16*)ws;   ws += (size_t)S_ * 512 * C_ * 2;   // 4.2 MB
    _Float16* Wh     = (_Float16*)ws;   ws += (size_t)S_ * 512 * C_ * 2;   // 4.2 MB
    _Float16* f2h    = (_Float16*)ws;   ws += (size_t)S_ * C_ * 512 * 2;   // 4.2 MB
    _Float16* f2th   = (_Float16*)ws;   ws += (size_t)S_ * 512 * C_ * 2;   // 4.2 MB
    _Float16* maskh  = (_Float16*)ws;   ws += (size_t)S_ * MP2 * 2;        // 7.5 MB
    float* num       = (float*)ws;      ws += (size_t)S_ * P_ * 4;
    float* den       = (float*)ws;      ws += (size_t)S_ * P_ * 4;

    k_maps<<<8, 256, 0, stream>>>(lw, mw, sw, map4t);
    k_winit<<<dim3(128, S_), 256, 0, stream>>>(filt, Wf, Wh, num, den);
    k_trans<<<dim3(16, 8, S_), 256, 0, stream>>>(feat, f2h, f2th);

    for (int it = 0; it < 3; ++it) {
        // GEMM1: A=Wh [512x256], B=f2th [512x256], K=256 -> residh(all)/maskh
        k_gemm<1, 256, 256, 256><<<dim3(16, 8, 8), 256, 0, stream>>>(
            Wh, f2th, map4t, nullptr, nullptr, nullptr, residh, maskh, nullptr);
        // GEMM2: A=residh [512x512], B=f2h [256x512], K=512 -> wgradh + num
        k_gemm<2, 512, 512, 512><<<dim3(16, 8, 4), 256, 0, stream>>>(
            residh, f2h, map4t, nullptr, Wh, freg, wgradh, nullptr, num);
        // GEMM3: A=wgradh [512x256], B=f2th [512x256], K=256 -> den
        k_gemm<3, 256, 256, 256><<<dim3(16, 8, 8), 256, 0, stream>>>(
            wgradh, f2th, map4t, maskh, nullptr, nullptr, nullptr, nullptr, den);
        k_update<<<dim3(121, S_), 256, 0, stream>>>(Wf, wgradh, num, den, freg, lsl, Wh);
    }
}

// Round 7
// 140.080 us; speedup vs baseline: 4.5304x; 1.0455x over previous
//
#include <hip/hip_runtime.h>
#include <math.h>
#include <stdint.h>

#define Ww 22
#define P_ 484            // H*W (also number of filters)
#define S_ 16
#define C_ 256
#define MP2 234256        // 484*484
#define TSZ 1849          // 43*43 distance table

typedef _Float16 f16x8 __attribute__((ext_vector_type(8)));
typedef _Float16 f16x4 __attribute__((ext_vector_type(4)));
typedef float f32x4 __attribute__((ext_vector_type(4)));

// XCD-chunked remap: grid size n divisible by 8; XCD x (= bid%8) gets the
// contiguous wgid range [x*n/8, (x+1)*n/8) -> with s = wgid / (n/8/2) each
// XCD owns exactly 2 s-slices, identical across ALL kernels in the chain.
__device__ __forceinline__ int xcd_chunk(int bid, int chunk) {
    return (bid & 7) * chunk + (bid >> 3);
}

// ---- global_load_lds width-16 ----------------------------------------------
__device__ __forceinline__ void gld16(const _Float16* g, _Float16* lds) {
    auto* lp = (__attribute__((address_space(3))) uint32_t*)(uintptr_t)(lds);
    auto* gp = (const __attribute__((address_space(1))) uint32_t*)(uintptr_t)(g);
    __builtin_amdgcn_global_load_lds(gp, lp, 16, 0, 0);
}

// ---------------- maps table: 43x43 entries of (lab, a, sw2, spw) -----------
__global__ void k_maps(const float* __restrict__ label_w, const float* __restrict__ mask_w,
                       const float* __restrict__ spatial_w, f32x4* __restrict__ map4t) {
    int idx = blockIdx.x * blockDim.x + threadIdx.x;
    if (idx >= TSZ) return;
    int dx = idx / 43 - 21, dy = idx % 43 - 21;
    float d = sqrtf((float)(dx * dx + dy * dy)) * 2.0f;
    float lab = 0.f, msk = 0.f, spw = 0.f;
#pragma unroll
    for (int b = 0; b < 9; ++b) {
        float wb = fmaxf(0.f, 1.f - fabsf(d - (float)b));
        lab += wb * label_w[b];
        msk += wb * mask_w[b];
        spw += wb * spatial_w[b];
    }
    float w9 = fminf(fmaxf(1.f + (d - 9.f), 0.f), 1.f);
    lab += w9 * label_w[9];
    msk += w9 * mask_w[9];
    spw += w9 * spatial_w[9];
    f32x4 o;
    o[0] = lab;
    o[1] = 1.f / (1.f + expf(-msk));
    o[2] = spw * spw;
    o[3] = spw;
    map4t[idx] = o;
}

// ---------------- init: Wf = filt, Wh = f16(filt) (+zero pad rows) ----------
// 1D grid 2048 = 16s x 128 fblk, XCD-chunked (2 s per XCD)
__global__ __launch_bounds__(256) void k_winit(const float* __restrict__ filt,
                                               float* __restrict__ Wf, _Float16* __restrict__ Wh,
                                               float* __restrict__ num, float* __restrict__ den) {
    int wgid = xcd_chunk(blockIdx.x, 256);
    int s = wgid >> 7;
    int t = threadIdx.x;
    int f = (wgid & 127) * 4 + (t >> 6);   // 0..511
    int c = (t & 63) * 4;
    size_t oh = ((size_t)(s * 512 + f)) * C_ + c;
    if (f < P_) {
        size_t o = ((size_t)(s * P_ + f)) * C_ + c;
        f32x4 v = *(const f32x4*)(filt + o);
        *(f32x4*)(Wf + o) = v;
        f16x4 h;
#pragma unroll
        for (int q = 0; q < 4; ++q) h[q] = (_Float16)v[q];
        *(f16x4*)(Wh + oh) = h;
        if ((t & 63) == 0) { num[s * P_ + f] = 0.f; den[s * P_ + f] = 0.f; }
    } else {
        f16x4 h = {};
        *(f16x4*)(Wh + oh) = h;   // zero pad rows (A-operand of GEMM1)
    }
}

// ---------------- transpose+convert: f2h [s][256][512], f2th [s][512][256] --
// 1D grid 2048 = 16s x (16 pblk x 8 cblk), XCD-chunked
__global__ __launch_bounds__(256) void k_trans(const float* __restrict__ feat,
                                               _Float16* __restrict__ f2h,
                                               _Float16* __restrict__ f2th) {
    int wgid = xcd_chunk(blockIdx.x, 256);
    int s = wgid >> 7;
    int rem = wgid & 127;
    int p0 = (rem & 15) * 32, c0 = (rem >> 4) * 32;
    int cc = threadIdx.x & 31, rr = threadIdx.x >> 5;  // rr 0..7
    __shared__ float tb[32][33];
#pragma unroll
    for (int q = 0; q < 4; ++q) {
        int c = c0 + rr + q * 8;
        int p = p0 + cc;
        float v = (p < P_) ? feat[((size_t)s * C_ + c) * P_ + p] : 0.f;
        f2h[((size_t)s * C_ + c) * 512 + p] = (_Float16)v;
        tb[rr + q * 8][cc] = v;
    }
    __syncthreads();
#pragma unroll
    for (int q = 0; q < 4; ++q) {
        int p = p0 + rr + q * 8;   // rows >= 484 hold zeros
        f2th[((size_t)s * 512 + p) * C_ + c0 + cc] = (_Float16)tb[cc][rr + q * 8];
    }
}

// ---------------- fused MFMA GEMM, single-buffer LDS, BK=128 per barrier ----
// 64x64 tiles, 4 waves, TI=TJ=2; proven stage->sync->compute->sync loop.
// 1D grid, XCD-chunked so each XCD owns 2 s-slices (same 2 in all 3 GEMMs).
// EPI 1: scores -> residual(f16, pads zeroed) + mask(f16)   K=256, 1024 tiles
// EPI 2: wgrad  -> wgradh(f16,+reg*W) + atomic num          K=512,  512 tiles
// EPI 3: sgrad  -> atomic den                               K=256, 1024 tiles
template <int EPI, int KK, int LDA, int LDB, int TPS, int NBN>
__global__ __launch_bounds__(256, 4) void k_gemm(
    const _Float16* __restrict__ Ah, const _Float16* __restrict__ Bh,
    const f32x4* __restrict__ map4t, const _Float16* __restrict__ maskh_i,
    const _Float16* __restrict__ Wh_i, const float* __restrict__ freg,
    _Float16* __restrict__ out_h, _Float16* __restrict__ out_h2,
    float* __restrict__ red) {
    constexpr int TI = 2, TJ = 2, NT = KK / 128;
    int tid = threadIdx.x;
    int w = tid >> 6, l = tid & 63;
    int wgid = xcd_chunk(blockIdx.x, S_ * TPS / 8);
    int s = wgid / TPS;
    int rem = wgid % TPS;
    int m0 = (rem / NBN) * 64, n0 = (rem % NBN) * 64;   // n fastest: share A panel
    int wm = w >> 1, wn = w & 1;
    int r16 = l & 15;

    __shared__ _Float16 As[64 * 128];   // 16 KB
    __shared__ _Float16 Bs[64 * 128];   // 16 KB

    // staging: linear LDS dest (wave-uniform base + lane*16B).
    // invariant: LDS[row][g] = global[row][g ^ (row & 15)]  (16B granules)
    int lrow = w * 4 + (l >> 4);               // row & 15 for every issue (chunk stride 16)
    int gsrc = ((l & 15) ^ lrow) << 3;         // swizzled source granule, f16 units
    const _Float16* gA = Ah + (size_t)s * (512 * LDA) + (size_t)(m0 + lrow) * LDA + gsrc;
    const _Float16* gB = Bh + (size_t)s * 131072 + (size_t)(n0 + lrow) * LDB + gsrc;

    f32x4 acc[TI][TJ] = {};

#pragma unroll
    for (int t = 0; t < NT; ++t) {
        // ---- stage K-chunk t (128 wide): 4 issues/wave per operand ----
#pragma unroll
        for (int i = 0; i < 4; ++i) {
            gld16(gA + (size_t)i * 16 * LDA + t * 128, &As[(i * 16 + w * 4) * 128]);
            gld16(gB + (size_t)i * 16 * LDB + t * 128, &Bs[(i * 16 + w * 4) * 128]);
        }
        __syncthreads();   // drain vmcnt -> staged data visible to all waves
        // ---- compute: 4 MFMA k-slices of 32 ----
#pragma unroll
        for (int kk = 0; kk < 4; ++kk) {
            int px = ((kk * 4 + (l >> 4)) ^ r16) << 3;  // read-side XOR swizzle
            f16x8 af[TI], bf[TJ];
#pragma unroll
            for (int ti = 0; ti < TI; ++ti)
                af[ti] = *(const f16x8*)&As[(wm * 32 + ti * 16 + r16) * 128 + px];
#pragma unroll
            for (int tj = 0; tj < TJ; ++tj)
                bf[tj] = *(const f16x8*)&Bs[(wn * 32 + tj * 16 + r16) * 128 + px];
#pragma unroll
            for (int ti = 0; ti < TI; ++ti)
#pragma unroll
                for (int tj = 0; tj < TJ; ++tj)
                    acc[ti][tj] = __builtin_amdgcn_mfma_f32_16x16x32_f16(
                        af[ti], bf[tj], acc[ti][tj], 0, 0, 0);
        }
        if (t + 1 < NT) __syncthreads();   // protect LDS reuse (write-after-read)
    }

    // ---------------- epilogue ----------------
    int q4 = (l >> 4) * 4;

    if constexpr (EPI == 1) {
#pragma unroll
        for (int ti = 0; ti < TI; ++ti)
#pragma unroll
            for (int r = 0; r < 4; ++r) {
                int m = m0 + wm * 32 + ti * 16 + q4 + r;
                int im = m / 22, jm = m - im * 22;
#pragma unroll
                for (int tj = 0; tj < TJ; ++tj) {
                    int n = n0 + wn * 32 + tj * 16 + r16;
                    float res = 0.f;
                    if (m < P_ && n < P_) {
                        int kn = n / 22, ln = n - kn * 22;
                        f32x4 m4 = map4t[(kn - im + 21) * 43 + (ln - jm + 21)];
                        float sc = acc[ti][tj][r];
                        float sgn = (sc > 0.f) ? 1.f : ((sc < 0.f) ? -1.f : 0.f);
                        float msk = 0.5f * (1.f - m4[1]) * sgn + 0.5f * (1.f + m4[1]);
                        res = msk * (m4[2] * (msk * sc - m4[0]));
                        out_h2[(size_t)s * MP2 + (size_t)m * P_ + n] = (_Float16)msk;
                    }
                    out_h[((size_t)(s * 512 + m)) * 512 + n] = (_Float16)res;  // pads -> 0
                }
            }
    } else if constexpr (EPI == 2) {
        float fr = freg[0];
        float regw = fmaxf(fr * fr, 1e-10f);
#pragma unroll
        for (int ti = 0; ti < TI; ++ti)
#pragma unroll
            for (int r = 0; r < 4; ++r) {
                int m = m0 + wm * 32 + ti * 16 + q4 + r;
                float v = 0.f;
#pragma unroll
                for (int tj = 0; tj < TJ; ++tj) {
                    int n = n0 + wn * 32 + tj * 16 + r16;   // n < 256 always
                    size_t o = ((size_t)(s * 512 + m)) * C_ + n;
                    // pad rows: acc==0 and Wh==0 -> wg==0 (keeps wgradh pads zero)
                    float wg = acc[ti][tj][r] + regw * (float)Wh_i[o];
                    out_h[o] = (_Float16)wg;
                    v += wg * wg;
                }
                v += __shfl_xor(v, 1);
                v += __shfl_xor(v, 2);
                v += __shfl_xor(v, 4);
                v += __shfl_xor(v, 8);
                if (r16 == 0 && m < P_) atomicAdd(&red[s * P_ + m], v);
            }
    } else {
#pragma unroll
        for (int ti = 0; ti < TI; ++ti)
#pragma unroll
            for (int r = 0; r < 4; ++r) {
                int m = m0 + wm * 32 + ti * 16 + q4 + r;
                int im = m / 22, jm = m - im * 22;
                float v = 0.f;
#pragma unroll
                for (int tj = 0; tj < TJ; ++tj) {
                    int n = n0 + wn * 32 + tj * 16 + r16;
                    if (m < P_ && n < P_) {
                        int kn = n / 22, ln = n - kn * 22;
                        float spw = map4t[(kn - im + 21) * 43 + (ln - jm + 21)][3];
                        float msk = (float)maskh_i[(size_t)s * MP2 + (size_t)m * P_ + n];
                        float sg = spw * msk * acc[ti][tj][r];
                        v += sg * sg;
                    }
                }
                v += __shfl_xor(v, 1);
                v += __shfl_xor(v, 2);
                v += __shfl_xor(v, 4);
                v += __shfl_xor(v, 8);
                if (r16 == 0 && m < P_) atomicAdd(&red[s * P_ + m], v);
            }
    }
}

// ---------------- update: alpha + w step + f16 copy + zero reductions -------
// 1D grid 1936 = 16s x 121, XCD-chunked (242/XCD -> same 2 s per XCD)
__global__ __launch_bounds__(256) void k_update(float* __restrict__ Wf,
                                                const _Float16* __restrict__ wgradh,
                                                float* __restrict__ num, float* __restrict__ den,
                                                const float* __restrict__ freg,
                                                const float* __restrict__ lsl,
                                                _Float16* __restrict__ Wh) {
    int wgid = xcd_chunk(blockIdx.x, 242);
    int s = wgid / 121;
    int t = threadIdx.x;
    int f = (wgid % 121) * 4 + (t >> 6);
    int row = s * P_ + f;
    float nu = num[row], de = den[row];
    float fr = freg[0];
    float regw = fmaxf(fr * fr, 1e-10f);
    float alpha = nu / fmaxf(de + regw * nu, 1e-8f);
    float sa = expf(lsl[0]) * alpha;
    int c = (t & 63) * 4;
    size_t o = (size_t)row * C_ + c;
    size_t oh = ((size_t)(s * 512 + f)) * C_ + c;
    f32x4 wv = *(const f32x4*)(Wf + o);
    f16x4 g = *(const f16x4*)(wgradh + oh);
    f16x4 h;
#pragma unroll
    for (int q = 0; q < 4; ++q) {
        wv[q] -= sa * (float)g[q];
        h[q] = (_Float16)wv[q];
    }
    *(f32x4*)(Wf + o) = wv;
    *(f16x4*)(Wh + oh) = h;
    if ((t & 63) == 0) { num[row] = 0.f; den[row] = 0.f; }
}

// ---------------- launch -----------------------------------------------------
extern "C" void kernel_launch(void* const* d_in, const int* in_sizes, int n_in,
                              void* d_out, int out_size, void* d_ws, size_t ws_size,
                              hipStream_t stream) {
    const float* filt = (const float*)d_in[0];
    const float* feat = (const float*)d_in[1];
    const float* lsl  = (const float*)d_in[2];
    const float* freg = (const float*)d_in[3];
    const float* lw   = (const float*)d_in[4];
    const float* mw   = (const float*)d_in[5];
    const float* sw   = (const float*)d_in[6];
    float* Wf = (float*)d_out;

    // workspace carve (bytes)
    char* ws = (char*)d_ws;
    f32x4* map4t     = (f32x4*)ws;      ws += (size_t)TSZ * 16;            // 29.6 KB
    _Float16* residh = (_Float16*)ws;   ws += (size_t)S_ * 512 * 512 * 2;  // 8.4 MB
    _Float16* wgradh = (_Float16*)ws;   ws += (size_t)S_ * 512 * C_ * 2;   // 4.2 MB
    _Float16* Wh     = (_Float16*)ws;   ws += (size_t)S_ * 512 * C_ * 2;   // 4.2 MB
    _Float16* f2h    = (_Float16*)ws;   ws += (size_t)S_ * C_ * 512 * 2;   // 4.2 MB
    _Float16* f2th   = (_Float16*)ws;   ws += (size_t)S_ * 512 * C_ * 2;   // 4.2 MB
    _Float16* maskh  = (_Float16*)ws;   ws += (size_t)S_ * MP2 * 2;        // 7.5 MB
    float* num       = (float*)ws;      ws += (size_t)S_ * P_ * 4;
    float* den       = (float*)ws;      ws += (size_t)S_ * P_ * 4;

    k_maps<<<8, 256, 0, stream>>>(lw, mw, sw, map4t);
    k_winit<<<2048, 256, 0, stream>>>(filt, Wf, Wh, num, den);
    k_trans<<<2048, 256, 0, stream>>>(feat, f2h, f2th);

    for (int it = 0; it < 3; ++it) {
        // GEMM1: A=Wh [512x256], B=f2th [512x256], K=256 -> residh(all)/maskh
        k_gemm<1, 256, 256, 256, 64, 8><<<1024, 256, 0, stream>>>(
            Wh, f2th, map4t, nullptr, nullptr, nullptr, residh, maskh, nullptr);
        // GEMM2: A=residh [512x512], B=f2h [256x512], K=512 -> wgradh + num
        k_gemm<2, 512, 512, 512, 32, 4><<<512, 256, 0, stream>>>(
            residh, f2h, map4t, nullptr, Wh, freg, wgradh, nullptr, num);
        // GEMM3: A=wgradh [512x256], B=f2th [512x256], K=256 -> den
        k_gemm<3, 256, 256, 256, 64, 8><<<1024, 256, 0, stream>>>(
            wgradh, f2th, map4t, maskh, nullptr, nullptr, nullptr, nullptr, den);
        k_update<<<1936, 256, 0, stream>>>(Wf, wgradh, num, den, freg, lsl, Wh);
    }
}

// Round 8
// 129.055 us; speedup vs baseline: 4.9174x; 1.0854x over previous
//
#include <hip/hip_runtime.h>
#include <math.h>
#include <stdint.h>

#define Ww 22
#define P_ 484            // H*W (also number of filters)
#define S_ 16
#define C_ 256
#define TSZ 1849          // 43*43 distance table

typedef _Float16 f16x8 __attribute__((ext_vector_type(8)));
typedef _Float16 f16x4 __attribute__((ext_vector_type(4)));
typedef float f32x4 __attribute__((ext_vector_type(4)));

// XCD-chunked remap: grid size n divisible by 8; XCD x (= bid%8) gets the
// contiguous wgid range [x*n/8,(x+1)*n/8) -> each XCD owns the SAME 2
// s-slices across every kernel in the chain (producer/consumer L2 locality).
__device__ __forceinline__ int xcd_chunk(int bid, int chunk) {
    return (bid & 7) * chunk + (bid >> 3);
}

// ---- global_load_lds width-16 ----------------------------------------------
__device__ __forceinline__ void gld16(const _Float16* g, _Float16* lds) {
    auto* lp = (__attribute__((address_space(3))) uint32_t*)(uintptr_t)(lds);
    auto* gp = (const __attribute__((address_space(1))) uint32_t*)(uintptr_t)(g);
    __builtin_amdgcn_global_load_lds(gp, lp, 16, 0, 0);
}

__device__ __forceinline__ f32x4 map_entry(const float* label_w, const float* mask_w,
                                           const float* spatial_w, float d) {
    float lab = 0.f, msk = 0.f, spw = 0.f;
#pragma unroll
    for (int b = 0; b < 9; ++b) {
        float wb = fmaxf(0.f, 1.f - fabsf(d - (float)b));
        lab += wb * label_w[b];
        msk += wb * mask_w[b];
        spw += wb * spatial_w[b];
    }
    float w9 = fminf(fmaxf(1.f + (d - 9.f), 0.f), 1.f);
    lab += w9 * label_w[9];
    msk += w9 * mask_w[9];
    spw += w9 * spatial_w[9];
    f32x4 o;
    o[0] = lab;
    o[1] = 1.f / (1.f + expf(-msk));
    o[2] = spw * spw;
    o[3] = spw;
    return o;
}

// ---------------- merged prologue: maps + winit + trans ---------------------
// grid 4112 = 8 XCD-chunks x 514: local 0 = maps slice; 1..256 = winit;
// 257..512 = trans; 513 idle. Branch is block-uniform (syncthreads safe).
__global__ __launch_bounds__(256) void k_pro(
    const float* __restrict__ filt, const float* __restrict__ feat,
    const float* __restrict__ lw, const float* __restrict__ mw,
    const float* __restrict__ sw,
    float* __restrict__ Wf, _Float16* __restrict__ Wh,
    float* __restrict__ num0, float* __restrict__ den0,
    _Float16* __restrict__ f2h, _Float16* __restrict__ f2th,
    f32x4* __restrict__ map4t) {
    int wgid = xcd_chunk(blockIdx.x, 514);
    int x = wgid / 514;
    int local = wgid % 514;
    int t = threadIdx.x;
    if (local == 0) {
        int idx = x + 8 * t;     // covers idx == x (mod 8), 8*256 > TSZ
        if (idx < TSZ) {
            int dx = idx / 43 - 21, dy = idx % 43 - 21;
            float d = sqrtf((float)(dx * dx + dy * dy)) * 2.0f;
            map4t[idx] = map_entry(lw, mw, sw, d);
        }
    } else if (local < 257) {
        int u = local - 1;
        int s = x * 2 + (u >> 7);
        int f = (u & 127) * 4 + (t >> 6);   // 0..511
        int c = (t & 63) * 4;
        size_t oh = ((size_t)(s * 512 + f)) * C_ + c;
        if (f < P_) {
            size_t o = ((size_t)(s * P_ + f)) * C_ + c;
            f32x4 v = *(const f32x4*)(filt + o);
            *(f32x4*)(Wf + o) = v;
            f16x4 h;
#pragma unroll
            for (int q = 0; q < 4; ++q) h[q] = (_Float16)v[q];
            *(f16x4*)(Wh + oh) = h;
            if ((t & 63) == 0) { num0[s * P_ + f] = 0.f; den0[s * P_ + f] = 0.f; }
        } else {
            f16x4 h = {};
            *(f16x4*)(Wh + oh) = h;   // zero pad rows
        }
    } else if (local < 513) {
        int u = local - 257;
        int s = x * 2 + (u >> 7);
        int rem = u & 127;
        int p0 = (rem & 15) * 32, c0 = (rem >> 4) * 32;
        int cc = t & 31, rr = t >> 5;
        __shared__ float tb[32][33];
#pragma unroll
        for (int q = 0; q < 4; ++q) {
            int c = c0 + rr + q * 8;
            int p = p0 + cc;
            float v = (p < P_) ? feat[((size_t)s * C_ + c) * P_ + p] : 0.f;
            f2h[((size_t)s * C_ + c) * 512 + p] = (_Float16)v;
            tb[rr + q * 8][cc] = v;
        }
        __syncthreads();
#pragma unroll
        for (int q = 0; q < 4; ++q) {
            int p = p0 + rr + q * 8;   // rows >= 484 hold zeros
            f2th[((size_t)s * 512 + p) * C_ + c0 + cc] = (_Float16)tb[cc][rr + q * 8];
        }
    }
}

// ---------------- fused MFMA GEMM, single-buffer LDS, BK=128 per barrier ----
// 64x64 tiles, 4 waves, TI=TJ=2; proven stage->sync->compute->sync loop.
// EPI 1: scores -> scoresh(raw,f16) + residual(f16) + mask(f16)
// EPI 2: wgrad  -> wgradh(f16,+reg*W) + atomic num
// EPI 3: sgrad  -> atomic den (+ optional sgraw write via WSG)
template <int EPI, int KK, int LDA, int LDB, int TPS, int NBN, bool WSG = false>
__global__ __launch_bounds__(256, 4) void k_gemm(
    const _Float16* __restrict__ Ah, const _Float16* __restrict__ Bh,
    const f32x4* __restrict__ map4t, const _Float16* __restrict__ maskh_i,
    const _Float16* __restrict__ Wh_i, const float* __restrict__ freg,
    _Float16* __restrict__ out_h, _Float16* __restrict__ out_h2,
    _Float16* __restrict__ out_h3, float* __restrict__ red) {
    constexpr int TI = 2, TJ = 2, NT = KK / 128;
    int tid = threadIdx.x;
    int w = tid >> 6, l = tid & 63;
    int wgid = xcd_chunk(blockIdx.x, S_ * TPS / 8);
    int s = wgid / TPS;
    int rem = wgid % TPS;
    int m0 = (rem / NBN) * 64, n0 = (rem % NBN) * 64;   // n fastest: share A panel
    int wm = w >> 1, wn = w & 1;
    int r16 = l & 15;

    __shared__ _Float16 As[64 * 128];   // 16 KB
    __shared__ _Float16 Bs[64 * 128];   // 16 KB

    // staging: linear LDS dest (wave-uniform base + lane*16B).
    // invariant: LDS[row][g] = global[row][g ^ (row & 15)]  (16B granules)
    int lrow = w * 4 + (l >> 4);               // row & 15 for every issue
    int gsrc = ((l & 15) ^ lrow) << 3;         // swizzled source granule
    const _Float16* gA = Ah + (size_t)s * (512 * LDA) + (size_t)(m0 + lrow) * LDA + gsrc;
    const _Float16* gB = Bh + (size_t)s * 131072 + (size_t)(n0 + lrow) * LDB + gsrc;

    f32x4 acc[TI][TJ] = {};

#pragma unroll
    for (int t = 0; t < NT; ++t) {
#pragma unroll
        for (int i = 0; i < 4; ++i) {
            gld16(gA + (size_t)i * 16 * LDA + t * 128, &As[(i * 16 + w * 4) * 128]);
            gld16(gB + (size_t)i * 16 * LDB + t * 128, &Bs[(i * 16 + w * 4) * 128]);
        }
        __syncthreads();   // drain vmcnt -> staged data visible to all waves
#pragma unroll
        for (int kk = 0; kk < 4; ++kk) {
            int px = ((kk * 4 + (l >> 4)) ^ r16) << 3;  // read-side XOR swizzle
            f16x8 af[TI], bf[TJ];
#pragma unroll
            for (int ti = 0; ti < TI; ++ti)
                af[ti] = *(const f16x8*)&As[(wm * 32 + ti * 16 + r16) * 128 + px];
#pragma unroll
            for (int tj = 0; tj < TJ; ++tj)
                bf[tj] = *(const f16x8*)&Bs[(wn * 32 + tj * 16 + r16) * 128 + px];
#pragma unroll
            for (int ti = 0; ti < TI; ++ti)
#pragma unroll
                for (int tj = 0; tj < TJ; ++tj)
                    acc[ti][tj] = __builtin_amdgcn_mfma_f32_16x16x32_f16(
                        af[ti], bf[tj], acc[ti][tj], 0, 0, 0);
        }
        if (t + 1 < NT) __syncthreads();   // protect LDS reuse
    }

    // ---------------- epilogue ----------------
    int q4 = (l >> 4) * 4;

    if constexpr (EPI == 1) {
#pragma unroll
        for (int ti = 0; ti < TI; ++ti)
#pragma unroll
            for (int r = 0; r < 4; ++r) {
                int m = m0 + wm * 32 + ti * 16 + q4 + r;
                int im = m / 22, jm = m - im * 22;
#pragma unroll
                for (int tj = 0; tj < TJ; ++tj) {
                    int n = n0 + wn * 32 + tj * 16 + r16;
                    float sc = acc[ti][tj][r];     // pads -> 0 (zero operands)
                    float res = 0.f;
                    size_t po = ((size_t)(s * 512 + m)) * 512 + n;
                    if (m < P_ && n < P_) {
                        int kn = n / 22, ln = n - kn * 22;
                        f32x4 m4 = map4t[(kn - im + 21) * 43 + (ln - jm + 21)];
                        float sgn = (sc > 0.f) ? 1.f : ((sc < 0.f) ? -1.f : 0.f);
                        float msk = 0.5f * (1.f - m4[1]) * sgn + 0.5f * (1.f + m4[1]);
                        res = msk * (m4[2] * (msk * sc - m4[0]));
                        out_h2[po] = (_Float16)msk;
                    }
                    out_h[po] = (_Float16)res;     // residh (pads -> 0)
                    out_h3[po] = (_Float16)sc;     // scoresh (pads -> 0)
                }
            }
    } else if constexpr (EPI == 2) {
        float fr = freg[0];
        float regw = fmaxf(fr * fr, 1e-10f);
#pragma unroll
        for (int ti = 0; ti < TI; ++ti)
#pragma unroll
            for (int r = 0; r < 4; ++r) {
                int m = m0 + wm * 32 + ti * 16 + q4 + r;
                float v = 0.f;
#pragma unroll
                for (int tj = 0; tj < TJ; ++tj) {
                    int n = n0 + wn * 32 + tj * 16 + r16;   // n < 256 always
                    size_t o = ((size_t)(s * 512 + m)) * C_ + n;
                    // pad rows: acc==0 and Wh==0 -> wg==0 (wgradh pads stay 0)
                    float wg = acc[ti][tj][r] + regw * (float)Wh_i[o];
                    out_h[o] = (_Float16)wg;
                    v += wg * wg;
                }
                v += __shfl_xor(v, 1);
                v += __shfl_xor(v, 2);
                v += __shfl_xor(v, 4);
                v += __shfl_xor(v, 8);
                if (r16 == 0 && m < P_) atomicAdd(&red[s * P_ + m], v);
            }
    } else {
#pragma unroll
        for (int ti = 0; ti < TI; ++ti)
#pragma unroll
            for (int r = 0; r < 4; ++r) {
                int m = m0 + wm * 32 + ti * 16 + q4 + r;
                int im = m / 22, jm = m - im * 22;
                float v = 0.f;
#pragma unroll
                for (int tj = 0; tj < TJ; ++tj) {
                    int n = n0 + wn * 32 + tj * 16 + r16;
                    float sc = acc[ti][tj][r];
                    if constexpr (WSG)
                        out_h[((size_t)(s * 512 + m)) * 512 + n] = (_Float16)sc;  // sgraw
                    if (m < P_ && n < P_) {
                        int kn = n / 22, ln = n - kn * 22;
                        float spw = map4t[(kn - im + 21) * 43 + (ln - jm + 21)][3];
                        float msk = (float)maskh_i[((size_t)(s * 512 + m)) * 512 + n];
                        float sg = spw * msk * sc;
                        v += sg * sg;
                    }
                }
                v += __shfl_xor(v, 1);
                v += __shfl_xor(v, 2);
                v += __shfl_xor(v, 4);
                v += __shfl_xor(v, 8);
                if (r16 == 0 && m < P_) atomicAdd(&red[s * P_ + m], v);
            }
    }
}

// ---------------- fused: W-update + scores recurrence + residual epilogue ---
// grid 3872, chunk 484 (2 s per XCD, aligned with GEMMs).
// local<121: W rows (Wf,Wh update; zero the OTHER num/den bank)
// local>=121: scores(it+1) = scores(it) - sa*sgraw; residual/mask epilogue
__global__ __launch_bounds__(256) void k_fu(
    float* __restrict__ Wf, _Float16* __restrict__ Wh,
    const _Float16* __restrict__ wgradh,
    const float* __restrict__ num_rd, const float* __restrict__ den_rd,
    float* __restrict__ num_zw, float* __restrict__ den_zw,
    const _Float16* __restrict__ sgrawh, _Float16* __restrict__ scoresh,
    _Float16* __restrict__ residh, _Float16* __restrict__ maskh,
    const f32x4* __restrict__ map4t,
    const float* __restrict__ freg, const float* __restrict__ lsl) {
    int wgid = xcd_chunk(blockIdx.x, 484);
    int s = wgid / 242;
    int local = wgid % 242;
    int t = threadIdx.x;
    float fr = freg[0];
    float regw = fmaxf(fr * fr, 1e-10f);
    float step = expf(lsl[0]);
    if (local < 121) {
        int f = local * 4 + (t >> 6);
        int row = s * P_ + f;
        float nu = num_rd[row], de = den_rd[row];
        float sa = step * (nu / fmaxf(de + regw * nu, 1e-8f));
        int c = (t & 63) * 4;
        size_t o = (size_t)row * C_ + c;
        size_t oh = ((size_t)(s * 512 + f)) * C_ + c;
        f32x4 wv = *(const f32x4*)(Wf + o);
        f16x4 g = *(const f16x4*)(wgradh + oh);
        f16x4 h;
#pragma unroll
        for (int q = 0; q < 4; ++q) {
            wv[q] -= sa * (float)g[q];
            h[q] = (_Float16)wv[q];
        }
        *(f32x4*)(Wf + o) = wv;
        *(f16x4*)(Wh + oh) = h;
        if ((t & 63) == 0) { num_zw[row] = 0.f; den_zw[row] = 0.f; }
    } else {
        int m = (local - 121) * 4 + (t >> 6);   // < 484
        int row = s * P_ + m;
        float nu = num_rd[row], de = den_rd[row];
        float sa = step * (nu / fmaxf(de + regw * nu, 1e-8f));
        int im = m / 22, jm = m - im * 22;
        int n0 = (t & 63) * 8;
        size_t ro = ((size_t)(s * 512 + m)) * 512 + n0;
        f16x8 so = *(const f16x8*)(scoresh + ro);
        f16x8 gg = *(const f16x8*)(sgrawh + ro);
        f16x8 sn, rs, mk;
#pragma unroll
        for (int j = 0; j < 8; ++j) {
            float sc = (float)so[j] - sa * (float)gg[j];
            sn[j] = (_Float16)sc;
            int n = n0 + j;
            float res = 0.f, msk = 0.f;
            if (n < P_) {
                int kn = n / 22, ln = n - kn * 22;
                f32x4 m4 = map4t[(kn - im + 21) * 43 + (ln - jm + 21)];
                float sgn = (sc > 0.f) ? 1.f : ((sc < 0.f) ? -1.f : 0.f);
                msk = 0.5f * (1.f - m4[1]) * sgn + 0.5f * (1.f + m4[1]);
                res = msk * (m4[2] * (msk * sc - m4[0]));
            }
            rs[j] = (_Float16)res;
            mk[j] = (_Float16)msk;
        }
        *(f16x8*)(scoresh + ro) = sn;
        *(f16x8*)(residh + ro) = rs;
        *(f16x8*)(maskh + ro) = mk;
    }
}

// ---------------- final update: alpha + w step ------------------------------
__global__ __launch_bounds__(256) void k_update(float* __restrict__ Wf,
                                                const _Float16* __restrict__ wgradh,
                                                const float* __restrict__ num,
                                                const float* __restrict__ den,
                                                const float* __restrict__ freg,
                                                const float* __restrict__ lsl) {
    int wgid = xcd_chunk(blockIdx.x, 242);
    int s = wgid / 121;
    int t = threadIdx.x;
    int f = (wgid % 121) * 4 + (t >> 6);
    int row = s * P_ + f;
    float nu = num[row], de = den[row];
    float fr = freg[0];
    float regw = fmaxf(fr * fr, 1e-10f);
    float sa = expf(lsl[0]) * (nu / fmaxf(de + regw * nu, 1e-8f));
    int c = (t & 63) * 4;
    size_t o = (size_t)row * C_ + c;
    size_t oh = ((size_t)(s * 512 + f)) * C_ + c;
    f32x4 wv = *(const f32x4*)(Wf + o);
    f16x4 g = *(const f16x4*)(wgradh + oh);
#pragma unroll
    for (int q = 0; q < 4; ++q) wv[q] -= sa * (float)g[q];
    *(f32x4*)(Wf + o) = wv;
}

// ---------------- launch -----------------------------------------------------
extern "C" void kernel_launch(void* const* d_in, const int* in_sizes, int n_in,
                              void* d_out, int out_size, void* d_ws, size_t ws_size,
                              hipStream_t stream) {
    const float* filt = (const float*)d_in[0];
    const float* feat = (const float*)d_in[1];
    const float* lsl  = (const float*)d_in[2];
    const float* freg = (const float*)d_in[3];
    const float* lw   = (const float*)d_in[4];
    const float* mw   = (const float*)d_in[5];
    const float* sw   = (const float*)d_in[6];
    float* Wf = (float*)d_out;

    // workspace carve (bytes)
    char* ws = (char*)d_ws;
    f32x4* map4t     = (f32x4*)ws;      ws += (size_t)TSZ * 16;            // 29.6 KB
    _Float16* residh = (_Float16*)ws;   ws += (size_t)S_ * 512 * 512 * 2;  // 8.4 MB
    _Float16* scoresh= (_Float16*)ws;   ws += (size_t)S_ * 512 * 512 * 2;  // 8.4 MB
    _Float16* sgrawh = (_Float16*)ws;   ws += (size_t)S_ * 512 * 512 * 2;  // 8.4 MB
    _Float16* maskh  = (_Float16*)ws;   ws += (size_t)S_ * 512 * 512 * 2;  // 8.4 MB
    _Float16* wgradh = (_Float16*)ws;   ws += (size_t)S_ * 512 * C_ * 2;   // 4.2 MB
    _Float16* Wh     = (_Float16*)ws;   ws += (size_t)S_ * 512 * C_ * 2;   // 4.2 MB
    _Float16* f2h    = (_Float16*)ws;   ws += (size_t)S_ * C_ * 512 * 2;   // 4.2 MB
    _Float16* f2th   = (_Float16*)ws;   ws += (size_t)S_ * 512 * C_ * 2;   // 4.2 MB
    float* num0      = (float*)ws;      ws += (size_t)S_ * P_ * 4;
    float* den0      = (float*)ws;      ws += (size_t)S_ * P_ * 4;
    float* num1      = (float*)ws;      ws += (size_t)S_ * P_ * 4;
    float* den1      = (float*)ws;      ws += (size_t)S_ * P_ * 4;

    // prologue: maps + winit (zeroes bank0) + trans
    k_pro<<<4112, 256, 0, stream>>>(filt, feat, lw, mw, sw, Wf, Wh, num0, den0,
                                    f2h, f2th, map4t);

    // ---- iteration 0 ----
    k_gemm<1, 256, 256, 256, 64, 8><<<1024, 256, 0, stream>>>(
        Wh, f2th, map4t, nullptr, nullptr, nullptr, residh, maskh, scoresh, nullptr);
    k_gemm<2, 512, 512, 512, 32, 4><<<512, 256, 0, stream>>>(
        residh, f2h, map4t, nullptr, Wh, freg, wgradh, nullptr, nullptr, num0);
    k_gemm<3, 256, 256, 256, 64, 8, true><<<1024, 256, 0, stream>>>(
        wgradh, f2th, map4t, maskh, nullptr, nullptr, sgrawh, nullptr, nullptr, den0);
    // ---- iteration 1 ----
    k_fu<<<3872, 256, 0, stream>>>(Wf, Wh, wgradh, num0, den0, num1, den1,
                                   sgrawh, scoresh, residh, maskh, map4t, freg, lsl);
    k_gemm<2, 512, 512, 512, 32, 4><<<512, 256, 0, stream>>>(
        residh, f2h, map4t, nullptr, Wh, freg, wgradh, nullptr, nullptr, num1);
    k_gemm<3, 256, 256, 256, 64, 8, true><<<1024, 256, 0, stream>>>(
        wgradh, f2th, map4t, maskh, nullptr, nullptr, sgrawh, nullptr, nullptr, den1);
    // ---- iteration 2 ----
    k_fu<<<3872, 256, 0, stream>>>(Wf, Wh, wgradh, num1, den1, num0, den0,
                                   sgrawh, scoresh, residh, maskh, map4t, freg, lsl);
    k_gemm<2, 512, 512, 512, 32, 4><<<512, 256, 0, stream>>>(
        residh, f2h, map4t, nullptr, Wh, freg, wgradh, nullptr, nullptr, num0);
    k_gemm<3, 256, 256, 256, 64, 8, false><<<1024, 256, 0, stream>>>(
        wgradh, f2th, map4t, maskh, nullptr, nullptr, nullptr, nullptr, nullptr, den0);
    // ---- final W step ----
    k_update<<<1936, 256, 0, stream>>>(Wf, wgradh, num0, den0, freg, lsl);
}